// Round 1
// baseline (431.815 us; speedup 1.0000x reference)
//
#include <hip/hip_runtime.h>

#define B_ 4
#define S_ 4096
#define E_ 1024
#define H_ 128
#define M_ (B_*S_)   // 16384

typedef __attribute__((ext_vector_type(8))) short bf16x8;
typedef __attribute__((ext_vector_type(4))) float f32x4;

__device__ inline ushort f2bf(float f) {
  union { float f; unsigned u; } v; v.f = f;
  unsigned r = v.u + 0x7fffu + ((v.u >> 16) & 1u);   // RNE
  return (ushort)(r >> 16);
}

// ---------- kernel 1: W [1024][128] f32 (x3) -> Wt [3][128][1024] bf16 ----------
__global__ __launch_bounds__(256) void wt_kernel(const float* __restrict__ Wq,
    const float* __restrict__ Wk, const float* __restrict__ Wv,
    ushort* __restrict__ Wt) {
  int bid = blockIdx.x;               // 384 = 3 mats * 4 h-tiles * 32 e-tiles
  int mat = bid >> 7;
  int rem = bid & 127;
  int ht = rem >> 5, et = rem & 31;
  const float* W = mat == 0 ? Wq : (mat == 1 ? Wk : Wv);
  int e0 = et * 32, h0 = ht * 32;
  __shared__ float tl[32][33];
  int t = threadIdx.x;
  int r = t >> 3, c = (t & 7) << 2;
  const float4 f = *(const float4*)(W + (size_t)(e0 + r) * H_ + h0 + c);
  tl[r][c] = f.x; tl[r][c+1] = f.y; tl[r][c+2] = f.z; tl[r][c+3] = f.w;
  __syncthreads();
  ushort4 o;
  o.x = f2bf(tl[c+0][r]); o.y = f2bf(tl[c+1][r]);
  o.z = f2bf(tl[c+2][r]); o.w = f2bf(tl[c+3][r]);
  *(ushort4*)(Wt + ((size_t)mat*H_ + h0 + r) * E_ + e0 + c) = o;
}

// ---------- kernel 2: fused QKV projection GEMM ----------
// x [16384][1024] f32 @ Wt[3][128][1024] bf16 -> q,k,v [16384][128] bf16
__global__ __launch_bounds__(256) void qkv_gemm(const float* __restrict__ x,
    const ushort* __restrict__ Wt, ushort* __restrict__ qo,
    ushort* __restrict__ ko, ushort* __restrict__ vo) {
  const int m0 = blockIdx.x * 64;
  const int tid = threadIdx.x;
  const int wave = tid >> 6, lane = tid & 63;
  const int col = lane & 15, quad = lane >> 4;
  __shared__ ushort xa[64 * 72];          // 64 rows x BK=64, stride 72 (144B: 16B-aligned, 2-way banks)
  f32x4 acc[4][6];
  #pragma unroll
  for (int i = 0; i < 4; i++)
    #pragma unroll
    for (int j = 0; j < 6; j++) acc[i][j] = (f32x4){0.f,0.f,0.f,0.f};

  const int sr = tid >> 2;                // staging row 0..63
  const int sc = (tid & 3) << 4;          // 0,16,32,48
  const float* xsrc = x + (size_t)(m0 + sr) * E_ + sc;
  ushort* xdst = xa + sr * 72 + sc;

  for (int kb = 0; kb < E_; kb += 64) {
    float4 f0 = *(const float4*)(xsrc + kb + 0);
    float4 f1 = *(const float4*)(xsrc + kb + 4);
    float4 f2 = *(const float4*)(xsrc + kb + 8);
    float4 f3 = *(const float4*)(xsrc + kb + 12);
    alignas(16) ushort us[16];
    us[0]=f2bf(f0.x); us[1]=f2bf(f0.y); us[2]=f2bf(f0.z); us[3]=f2bf(f0.w);
    us[4]=f2bf(f1.x); us[5]=f2bf(f1.y); us[6]=f2bf(f1.z); us[7]=f2bf(f1.w);
    us[8]=f2bf(f2.x); us[9]=f2bf(f2.y); us[10]=f2bf(f2.z); us[11]=f2bf(f2.w);
    us[12]=f2bf(f3.x); us[13]=f2bf(f3.y); us[14]=f2bf(f3.z); us[15]=f2bf(f3.w);
    *(uint4*)(xdst)     = *(uint4*)&us[0];
    *(uint4*)(xdst + 8) = *(uint4*)&us[8];
    __syncthreads();
    #pragma unroll
    for (int kc = 0; kc < 2; kc++) {
      bf16x8 af[4];
      #pragma unroll
      for (int mt = 0; mt < 4; mt++)
        af[mt] = *(const bf16x8*)(xa + (mt*16 + col)*72 + kc*32 + quad*8);
      #pragma unroll
      for (int nt = 0; nt < 6; nt++) {
        int n = wave*96 + nt*16 + col;    // 0..383
        bf16x8 bfv = *(const bf16x8*)(Wt + ((size_t)(n >> 7) * H_ + (n & 127)) * E_
                                      + kb + kc*32 + quad*8);
        #pragma unroll
        for (int mt = 0; mt < 4; mt++)
          acc[mt][nt] = __builtin_amdgcn_mfma_f32_16x16x32_bf16(af[mt], bfv, acc[mt][nt], 0, 0, 0);
      }
    }
    __syncthreads();
  }
  #pragma unroll
  for (int nt = 0; nt < 6; nt++) {
    int n = wave*96 + nt*16 + col;
    int mat = n >> 7, nw = n & 127;
    ushort* dst = (mat == 0 ? qo : (mat == 1 ? ko : vo));
    #pragma unroll
    for (int mt = 0; mt < 4; mt++) {
      int row = m0 + mt*16 + quad*4;
      #pragma unroll
      for (int r = 0; r < 4; r++)
        dst[(size_t)(row + r) * H_ + nw] = f2bf(acc[mt][nt][r]);
    }
  }
}

// ---------- kernel 3: v [4][4096][128] bf16 -> vT [4][128][4096] bf16 ----------
__global__ __launch_bounds__(256) void vt_kernel(const ushort* __restrict__ v,
                                                 ushort* __restrict__ vT) {
  int bid = blockIdx.x;                   // 256 = 4 b * 64 s-tiles
  int b = bid >> 6, st = bid & 63;
  int s0 = st * 64;
  __shared__ ushort tl[64][136];          // 272B stride: 16B aligned
  int t = threadIdx.x;
  {
    int r = t >> 2, c0 = (t & 3) << 5;
    const ushort* src = v + ((size_t)(b * S_ + s0 + r)) * H_ + c0;
    uint4 a0 = ((const uint4*)src)[0];
    uint4 a1 = ((const uint4*)src)[1];
    uint4 a2 = ((const uint4*)src)[2];
    uint4 a3 = ((const uint4*)src)[3];
    uint4* d = (uint4*)(&tl[r][c0]);
    d[0]=a0; d[1]=a1; d[2]=a2; d[3]=a3;
  }
  __syncthreads();
  {
    int h = t >> 1, sc = (t & 1) << 5;
    alignas(16) ushort buf[32];
    #pragma unroll
    for (int i = 0; i < 32; i++) buf[i] = tl[sc + i][h];
    ushort* d = vT + ((size_t)b * H_ + h) * S_ + s0 + sc;
    #pragma unroll
    for (int i = 0; i < 4; i++) ((uint4*)d)[i] = ((uint4*)buf)[i];
  }
}

// ---------- kernel 4: causal flash attention ----------
// q,k [4][4096][128] bf16; vT [4][128][4096] bf16; out [4][4096][128] f32
__global__ __launch_bounds__(256) void flash_kernel(const ushort* __restrict__ q,
    const ushort* __restrict__ k, const ushort* __restrict__ vT,
    float* __restrict__ out) {
  const float scale = 0.08838834764831845f;   // 1/sqrt(128)
  const float L2E = 1.44269504088896340736f;
  int wg = blockIdx.x;
  int b = wg >> 6, tile = wg & 63;
  int wave = threadIdx.x >> 6, lane = threadIdx.x & 63;
  int col = lane & 15, quad = lane >> 4;
  int q0 = tile * 64 + wave * 16;             // this wave's first q row
  const ushort* qb = q + (size_t)b * S_ * H_;
  const ushort* kb = k + (size_t)b * S_ * H_;
  const ushort* vb = vT + (size_t)b * H_ * S_;

  __shared__ ushort plds[4][16 * 40];         // per-wave P tile, stride 40 (80B)
  ushort* pw = &plds[wave][0];

  bf16x8 qf[4];
  const ushort* qptr = qb + (size_t)(q0 + col) * H_ + quad * 8;
  #pragma unroll
  for (int kc = 0; kc < 4; kc++) qf[kc] = *(const bf16x8*)(qptr + kc * 32);

  f32x4 O[8];
  #pragma unroll
  for (int d = 0; d < 8; d++) O[d] = (f32x4){0.f,0.f,0.f,0.f};
  float m_i[4], l_i[4];
  #pragma unroll
  for (int r = 0; r < 4; r++) { m_i[r] = -1e30f; l_i[r] = 0.f; }

  const int kend = q0 + 16;                   // keys 0..q0+15 (causal)
  for (int kb0 = 0; kb0 < kend; kb0 += 32) {
    f32x4 sc0 = (f32x4){0.f,0.f,0.f,0.f}, sc1 = (f32x4){0.f,0.f,0.f,0.f};
    const ushort* kp0 = kb + (size_t)(kb0 + col) * H_ + quad * 8;
    const ushort* kp1 = kp0 + 16 * H_;
    #pragma unroll
    for (int kc = 0; kc < 4; kc++) {
      bf16x8 kf0 = *(const bf16x8*)(kp0 + kc * 32);
      bf16x8 kf1 = *(const bf16x8*)(kp1 + kc * 32);
      sc0 = __builtin_amdgcn_mfma_f32_16x16x32_bf16(qf[kc], kf0, sc0, 0, 0, 0);
      sc1 = __builtin_amdgcn_mfma_f32_16x16x32_bf16(qf[kc], kf1, sc1, 0, 0, 0);
    }
    float s0[4], s1[4];
    #pragma unroll
    for (int r = 0; r < 4; r++) { s0[r] = sc0[r]*scale; s1[r] = sc1[r]*scale; }
    if (kb0 + 31 > q0) {                      // diagonal chunk: mask key > row
      #pragma unroll
      for (int r = 0; r < 4; r++) {
        int row = q0 + quad*4 + r;
        if (kb0 + col > row)      s0[r] = -1e30f;
        if (kb0 + 16 + col > row) s1[r] = -1e30f;
      }
    }
    float cm[4];
    #pragma unroll
    for (int r = 0; r < 4; r++) cm[r] = fmaxf(s0[r], s1[r]);
    #pragma unroll
    for (int off = 1; off <= 8; off <<= 1) {
      #pragma unroll
      for (int r = 0; r < 4; r++) cm[r] = fmaxf(cm[r], __shfl_xor(cm[r], off, 64));
    }
    float alpha[4], p0[4], p1[4], rs[4];
    #pragma unroll
    for (int r = 0; r < 4; r++) {
      float mn = fmaxf(m_i[r], cm[r]);
      alpha[r] = exp2f((m_i[r] - mn) * L2E);
      m_i[r] = mn;
      p0[r] = exp2f((s0[r] - mn) * L2E);
      p1[r] = exp2f((s1[r] - mn) * L2E);
      rs[r] = p0[r] + p1[r];
    }
    #pragma unroll
    for (int off = 1; off <= 8; off <<= 1) {
      #pragma unroll
      for (int r = 0; r < 4; r++) rs[r] += __shfl_xor(rs[r], off, 64);
    }
    #pragma unroll
    for (int r = 0; r < 4; r++) l_i[r] = l_i[r]*alpha[r] + rs[r];
    #pragma unroll
    for (int d = 0; d < 8; d++) {
      #pragma unroll
      for (int r = 0; r < 4; r++) O[d][r] *= alpha[r];
    }
    // P: C-layout -> LDS -> A-layout (bf16)
    #pragma unroll
    for (int r = 0; r < 4; r++) {
      pw[(quad*4 + r)*40 + col]      = f2bf(p0[r]);
      pw[(quad*4 + r)*40 + 16 + col] = f2bf(p1[r]);
    }
    bf16x8 pf = *(const bf16x8*)(pw + col*40 + quad*8);
    const ushort* vp = vb + kb0 + quad*8 + (size_t)col * S_;
    #pragma unroll
    for (int d = 0; d < 8; d++) {
      bf16x8 vf = *(const bf16x8*)(vp + (size_t)(d*16) * S_);
      O[d] = __builtin_amdgcn_mfma_f32_16x16x32_bf16(pf, vf, O[d], 0, 0, 0);
    }
  }
  float inv[4];
  #pragma unroll
  for (int r = 0; r < 4; r++) inv[r] = 1.f / l_i[r];
  #pragma unroll
  for (int d = 0; d < 8; d++) {
    #pragma unroll
    for (int r = 0; r < 4; r++)
      out[(size_t)(b*S_ + q0 + quad*4 + r) * H_ + d*16 + col] = O[d][r] * inv[r];
  }
}

extern "C" void kernel_launch(void* const* d_in, const int* in_sizes, int n_in,
                              void* d_out, int out_size, void* d_ws, size_t ws_size,
                              hipStream_t stream) {
  (void)in_sizes; (void)n_in; (void)out_size; (void)ws_size;
  const float* x  = (const float*)d_in[0];
  const float* Wq = (const float*)d_in[1];
  const float* Wk = (const float*)d_in[2];
  const float* Wv = (const float*)d_in[3];
  float* out = (float*)d_out;
  char* ws = (char*)d_ws;
  ushort* Wt = (ushort*)ws;                       // 3*128*1024*2 = 786432 B
  ushort* qb = (ushort*)(ws + 786432);            // 4 MB each
  ushort* kb = qb + (size_t)M_ * H_;
  ushort* vb = kb + (size_t)M_ * H_;
  ushort* vT = vb + (size_t)M_ * H_;

  hipLaunchKernelGGL(wt_kernel,   dim3(384), dim3(256), 0, stream, Wq, Wk, Wv, Wt);
  hipLaunchKernelGGL(qkv_gemm,    dim3(256), dim3(256), 0, stream, x, Wt, qb, kb, vb);
  hipLaunchKernelGGL(vt_kernel,   dim3(256), dim3(256), 0, stream, vb, vT);
  hipLaunchKernelGGL(flash_kernel,dim3(256), dim3(256), 0, stream, qb, kb, vT, out);
}

// Round 2
// 415.514 us; speedup vs baseline: 1.0392x; 1.0392x over previous
//
#include <hip/hip_runtime.h>

#define B_ 4
#define S_ 4096
#define E_ 1024
#define H_ 128
#define M_ (B_*S_)   // 16384

typedef __attribute__((ext_vector_type(8))) short bf16x8;
typedef __attribute__((ext_vector_type(4))) float f32x4;

__device__ inline ushort f2bf(float f) {
  union { float f; unsigned u; } v; v.f = f;
  unsigned r = v.u + 0x7fffu + ((v.u >> 16) & 1u);   // RNE
  return (ushort)(r >> 16);
}

// ---------- kernel 1: W [1024][128] f32 (x3) -> Wt [3][128][1024] bf16 ----------
__global__ __launch_bounds__(256) void wt_kernel(const float* __restrict__ Wq,
    const float* __restrict__ Wk, const float* __restrict__ Wv,
    ushort* __restrict__ Wt) {
  int bid = blockIdx.x;               // 384 = 3 mats * 4 h-tiles * 32 e-tiles
  int mat = bid >> 7;
  int rem = bid & 127;
  int ht = rem >> 5, et = rem & 31;
  const float* W = mat == 0 ? Wq : (mat == 1 ? Wk : Wv);
  int e0 = et * 32, h0 = ht * 32;
  __shared__ float tl[32][33];
  int t = threadIdx.x;
  int r = t >> 3, c = (t & 7) << 2;
  const float4 f = *(const float4*)(W + (size_t)(e0 + r) * H_ + h0 + c);
  tl[r][c] = f.x; tl[r][c+1] = f.y; tl[r][c+2] = f.z; tl[r][c+3] = f.w;
  __syncthreads();
  ushort4 o;
  o.x = f2bf(tl[c+0][r]); o.y = f2bf(tl[c+1][r]);
  o.z = f2bf(tl[c+2][r]); o.w = f2bf(tl[c+3][r]);
  *(ushort4*)(Wt + ((size_t)mat*H_ + h0 + r) * E_ + e0 + c) = o;
}

// ---------- kernel 2: fused QKV projection GEMM ----------
// x [16384][1024] f32 @ Wt[3][128][1024] bf16 -> q,k,v [16384][128] bf16
// M-tile 32, grid 512 -> 2 WG/CU (8 waves/CU) for latency hiding.
__global__ __launch_bounds__(256) void qkv_gemm(const float* __restrict__ x,
    const ushort* __restrict__ Wt, ushort* __restrict__ qo,
    ushort* __restrict__ ko, ushort* __restrict__ vo) {
  const int m0 = blockIdx.x * 32;
  const int tid = threadIdx.x;
  const int wave = tid >> 6, lane = tid & 63;
  const int col = lane & 15, quad = lane >> 4;
  __shared__ ushort xa[32 * 72];          // 32 rows x BK=64, stride 72
  f32x4 acc[2][6];
  #pragma unroll
  for (int i = 0; i < 2; i++)
    #pragma unroll
    for (int j = 0; j < 6; j++) acc[i][j] = (f32x4){0.f,0.f,0.f,0.f};

  const int sr = tid >> 3;                // staging row 0..31
  const int sc = (tid & 7) << 3;          // 0..56 step 8
  const float* xsrc = x + (size_t)(m0 + sr) * E_ + sc;
  ushort* xdst = xa + sr * 72 + sc;

  for (int kb = 0; kb < E_; kb += 64) {
    float4 f0 = *(const float4*)(xsrc + kb + 0);
    float4 f1 = *(const float4*)(xsrc + kb + 4);
    alignas(16) ushort us[8];
    us[0]=f2bf(f0.x); us[1]=f2bf(f0.y); us[2]=f2bf(f0.z); us[3]=f2bf(f0.w);
    us[4]=f2bf(f1.x); us[5]=f2bf(f1.y); us[6]=f2bf(f1.z); us[7]=f2bf(f1.w);
    *(uint4*)(xdst) = *(uint4*)&us[0];
    __syncthreads();
    #pragma unroll
    for (int kc = 0; kc < 2; kc++) {
      bf16x8 af[2];
      #pragma unroll
      for (int mt = 0; mt < 2; mt++)
        af[mt] = *(const bf16x8*)(xa + (mt*16 + col)*72 + kc*32 + quad*8);
      #pragma unroll
      for (int nt = 0; nt < 6; nt++) {
        int n = wave*96 + nt*16 + col;    // 0..383
        bf16x8 bfv = *(const bf16x8*)(Wt + ((size_t)(n >> 7) * H_ + (n & 127)) * E_
                                      + kb + kc*32 + quad*8);
        #pragma unroll
        for (int mt = 0; mt < 2; mt++)
          acc[mt][nt] = __builtin_amdgcn_mfma_f32_16x16x32_bf16(af[mt], bfv, acc[mt][nt], 0, 0, 0);
      }
    }
    __syncthreads();
  }
  #pragma unroll
  for (int nt = 0; nt < 6; nt++) {
    int n = wave*96 + nt*16 + col;
    int mat = n >> 7, nw = n & 127;
    ushort* dst = (mat == 0 ? qo : (mat == 1 ? ko : vo));
    #pragma unroll
    for (int mt = 0; mt < 2; mt++) {
      int row = m0 + mt*16 + quad*4;
      #pragma unroll
      for (int r = 0; r < 4; r++)
        dst[(size_t)(row + r) * H_ + nw] = f2bf(acc[mt][nt][r]);
    }
  }
}

// ---------- kernel 3: v [4][4096][128] bf16 -> vT [4][128][4096] bf16 ----------
__global__ __launch_bounds__(256) void vt_kernel(const ushort* __restrict__ v,
                                                 ushort* __restrict__ vT) {
  int bid = blockIdx.x;                   // 256 = 4 b * 64 s-tiles
  int b = bid >> 6, st = bid & 63;
  int s0 = st * 64;
  __shared__ ushort tl[64][136];
  int t = threadIdx.x;
  {
    int r = t >> 2, c0 = (t & 3) << 5;
    const ushort* src = v + ((size_t)(b * S_ + s0 + r)) * H_ + c0;
    uint4 a0 = ((const uint4*)src)[0];
    uint4 a1 = ((const uint4*)src)[1];
    uint4 a2 = ((const uint4*)src)[2];
    uint4 a3 = ((const uint4*)src)[3];
    uint4* d = (uint4*)(&tl[r][c0]);
    d[0]=a0; d[1]=a1; d[2]=a2; d[3]=a3;
  }
  __syncthreads();
  {
    int h = t >> 1, sc = (t & 1) << 5;
    alignas(16) ushort buf[32];
    #pragma unroll
    for (int i = 0; i < 32; i++) buf[i] = tl[sc + i][h];
    ushort* d = vT + ((size_t)b * H_ + h) * S_ + s0 + sc;
    #pragma unroll
    for (int i = 0; i < 4; i++) ((uint4*)d)[i] = ((uint4*)buf)[i];
  }
}

// ---------- kernel 4: causal flash attention, split-K ----------
// grid (c=8, t=64, b=4); chunk = keys [512c, 512c+512); invalid if t < 8c.
// Writes unnormalized partial O [64][128] f32 + (m,l) per row to ws.
#define CHUNK_ 512
__global__ __launch_bounds__(256) void flash_kernel(const ushort* __restrict__ q,
    const ushort* __restrict__ k, const ushort* __restrict__ vT,
    float* __restrict__ Opart, float* __restrict__ ml) {
  const float scale = 0.08838834764831845f;   // 1/sqrt(128)
  const float L2E = 1.44269504088896340736f;
  int c = blockIdx.x, tile = blockIdx.y, b = blockIdx.z;
  if (tile < 8 * c) return;                   // chunk beyond this tile's causal range
  int a = tile >> 3, rr = tile & 7;
  int slot = b * 288 + (a + 1) * (4 * a + rr) + c;

  int wave = threadIdx.x >> 6, lane = threadIdx.x & 63;
  int col = lane & 15, quad = lane >> 4;
  int q0 = tile * 64 + wave * 16;             // this wave's first q row
  const ushort* qb = q + (size_t)b * S_ * H_;
  const ushort* kb = k + (size_t)b * S_ * H_;
  const ushort* vb = vT + (size_t)b * H_ * S_;

  __shared__ ushort plds[4][16 * 40];         // per-wave P tile, stride 40 (80B)
  ushort* pw = &plds[wave][0];

  bf16x8 qf[4];
  const ushort* qptr = qb + (size_t)(q0 + col) * H_ + quad * 8;
  #pragma unroll
  for (int kc = 0; kc < 4; kc++) qf[kc] = *(const bf16x8*)(qptr + kc * 32);

  f32x4 O[8];
  #pragma unroll
  for (int d = 0; d < 8; d++) O[d] = (f32x4){0.f,0.f,0.f,0.f};
  float m_i[4], l_i[4];
  #pragma unroll
  for (int r = 0; r < 4; r++) { m_i[r] = -1e30f; l_i[r] = 0.f; }

  const int c0 = c * CHUNK_;
  const int kend = min(c0 + CHUNK_, q0 + 16);  // > c0 for all 4 waves (t >= 8c)
  for (int kb0 = c0; kb0 < kend; kb0 += 32) {
    f32x4 sc0 = (f32x4){0.f,0.f,0.f,0.f}, sc1 = (f32x4){0.f,0.f,0.f,0.f};
    const ushort* kp0 = kb + (size_t)(kb0 + col) * H_ + quad * 8;
    const ushort* kp1 = kp0 + 16 * H_;
    #pragma unroll
    for (int kc = 0; kc < 4; kc++) {
      bf16x8 kf0 = *(const bf16x8*)(kp0 + kc * 32);
      bf16x8 kf1 = *(const bf16x8*)(kp1 + kc * 32);
      sc0 = __builtin_amdgcn_mfma_f32_16x16x32_bf16(qf[kc], kf0, sc0, 0, 0, 0);
      sc1 = __builtin_amdgcn_mfma_f32_16x16x32_bf16(qf[kc], kf1, sc1, 0, 0, 0);
    }
    float s0[4], s1[4];
    #pragma unroll
    for (int r = 0; r < 4; r++) { s0[r] = sc0[r]*scale; s1[r] = sc1[r]*scale; }
    if (kb0 + 31 > q0) {                      // diagonal chunk: mask key > row
      #pragma unroll
      for (int r = 0; r < 4; r++) {
        int row = q0 + quad*4 + r;
        if (kb0 + col > row)      s0[r] = -1e30f;
        if (kb0 + 16 + col > row) s1[r] = -1e30f;
      }
    }
    float cm[4];
    #pragma unroll
    for (int r = 0; r < 4; r++) cm[r] = fmaxf(s0[r], s1[r]);
    #pragma unroll
    for (int off = 1; off <= 8; off <<= 1) {
      #pragma unroll
      for (int r = 0; r < 4; r++) cm[r] = fmaxf(cm[r], __shfl_xor(cm[r], off, 64));
    }
    float alpha[4], p0[4], p1[4], rs[4];
    #pragma unroll
    for (int r = 0; r < 4; r++) {
      float mn = fmaxf(m_i[r], cm[r]);
      alpha[r] = exp2f((m_i[r] - mn) * L2E);
      m_i[r] = mn;
      p0[r] = exp2f((s0[r] - mn) * L2E);
      p1[r] = exp2f((s1[r] - mn) * L2E);
      rs[r] = p0[r] + p1[r];
    }
    #pragma unroll
    for (int off = 1; off <= 8; off <<= 1) {
      #pragma unroll
      for (int r = 0; r < 4; r++) rs[r] += __shfl_xor(rs[r], off, 64);
    }
    #pragma unroll
    for (int r = 0; r < 4; r++) l_i[r] = l_i[r]*alpha[r] + rs[r];
    #pragma unroll
    for (int d = 0; d < 8; d++) {
      #pragma unroll
      for (int r = 0; r < 4; r++) O[d][r] *= alpha[r];
    }
    // P: C-layout -> LDS -> A-layout (bf16)
    #pragma unroll
    for (int r = 0; r < 4; r++) {
      pw[(quad*4 + r)*40 + col]      = f2bf(p0[r]);
      pw[(quad*4 + r)*40 + 16 + col] = f2bf(p1[r]);
    }
    bf16x8 pf = *(const bf16x8*)(pw + col*40 + quad*8);
    const ushort* vp = vb + kb0 + quad*8 + (size_t)col * S_;
    #pragma unroll
    for (int d = 0; d < 8; d++) {
      bf16x8 vf = *(const bf16x8*)(vp + (size_t)(d*16) * S_);
      O[d] = __builtin_amdgcn_mfma_f32_16x16x32_bf16(pf, vf, O[d], 0, 0, 0);
    }
  }
  // write unnormalized partials
  float* Op = Opart + (size_t)slot * (64 * 128);
  #pragma unroll
  for (int d = 0; d < 8; d++) {
    #pragma unroll
    for (int r = 0; r < 4; r++)
      Op[(wave*16 + quad*4 + r) * 128 + d*16 + col] = O[d][r];
  }
  if (col == 0) {
    #pragma unroll
    for (int r = 0; r < 4; r++) {
      int rl = wave*16 + quad*4 + r;
      ml[(size_t)slot*128 + rl*2]     = m_i[r];
      ml[(size_t)slot*128 + rl*2 + 1] = l_i[r];
    }
  }
}

// ---------- kernel 5: combine split-K partials ----------
__global__ __launch_bounds__(256) void combine_kernel(const float* __restrict__ Opart,
    const float* __restrict__ ml, float* __restrict__ out) {
  const float L2E = 1.44269504088896340736f;
  int tile = blockIdx.x, b = blockIdx.y;
  int a = tile >> 3, rr = tile & 7;
  int nc = a + 1;
  int base = b * 288 + (a + 1) * (4 * a + rr);
  int tid = threadIdx.x;
  int row = tid >> 2;                       // 0..63
  int cs = (tid & 3) * 4;                   // col group start
  float m_c[8], l_c[8];
  float mstar = -1e30f;
  for (int ci = 0; ci < nc; ci++) {
    m_c[ci] = ml[(size_t)(base + ci) * 128 + row * 2];
    l_c[ci] = ml[(size_t)(base + ci) * 128 + row * 2 + 1];
    mstar = fmaxf(mstar, m_c[ci]);
  }
  float denom = 0.f;
  float w_c[8];
  for (int ci = 0; ci < nc; ci++) {
    w_c[ci] = exp2f((m_c[ci] - mstar) * L2E);
    denom += w_c[ci] * l_c[ci];
  }
  float inv = 1.f / denom;
  f32x4 acc[8];
  #pragma unroll
  for (int i = 0; i < 8; i++) acc[i] = (f32x4){0.f,0.f,0.f,0.f};
  for (int ci = 0; ci < nc; ci++) {
    const float* Op = Opart + (size_t)(base + ci) * (64 * 128) + row * 128;
    float w = w_c[ci];
    #pragma unroll
    for (int i = 0; i < 8; i++) {
      f32x4 v = *(const f32x4*)(Op + cs + i * 16);
      acc[i] += w * v;
    }
  }
  float* o = out + ((size_t)(b * S_) + tile * 64 + row) * H_;
  #pragma unroll
  for (int i = 0; i < 8; i++) {
    f32x4 v = acc[i] * inv;
    *(f32x4*)(o + cs + i * 16) = v;
  }
}

extern "C" void kernel_launch(void* const* d_in, const int* in_sizes, int n_in,
                              void* d_out, int out_size, void* d_ws, size_t ws_size,
                              hipStream_t stream) {
  (void)in_sizes; (void)n_in; (void)out_size; (void)ws_size;
  const float* x  = (const float*)d_in[0];
  const float* Wq = (const float*)d_in[1];
  const float* Wk = (const float*)d_in[2];
  const float* Wv = (const float*)d_in[3];
  float* out = (float*)d_out;
  char* ws = (char*)d_ws;
  ushort* Wt = (ushort*)ws;                       // 786,432 B
  ushort* qb = (ushort*)(ws + 786432);            // 4 MB each
  ushort* kb = qb + (size_t)M_ * H_;
  ushort* vb = kb + (size_t)M_ * H_;
  ushort* vT = vb + (size_t)M_ * H_;
  float* Opart = (float*)(ws + 786432 + 4 * (size_t)M_ * H_ * 2);  // 1152*32KB
  float* ml = Opart + (size_t)1152 * 64 * 128;                     // 1152*512B

  hipLaunchKernelGGL(wt_kernel,   dim3(384), dim3(256), 0, stream, Wq, Wk, Wv, Wt);
  hipLaunchKernelGGL(qkv_gemm,    dim3(512), dim3(256), 0, stream, x, Wt, qb, kb, vb);
  hipLaunchKernelGGL(vt_kernel,   dim3(256), dim3(256), 0, stream, vb, vT);
  hipLaunchKernelGGL(flash_kernel,dim3(8, 64, 4), dim3(256), 0, stream, qb, kb, vT, Opart, ml);
  hipLaunchKernelGGL(combine_kernel, dim3(64, 4), dim3(256), 0, stream, Opart, ml, out);
}

// Round 3
// 404.572 us; speedup vs baseline: 1.0673x; 1.0270x over previous
//
#include <hip/hip_runtime.h>

#define B_ 4
#define S_ 4096
#define E_ 1024
#define H_ 128
#define M_ (B_*S_)   // 16384

typedef __attribute__((ext_vector_type(8))) short bf16x8;
typedef __attribute__((ext_vector_type(4))) float f32x4;

__device__ inline ushort f2bf(float f) {
  union { float f; unsigned u; } v; v.f = f;
  unsigned r = v.u + 0x7fffu + ((v.u >> 16) & 1u);   // RNE
  return (ushort)(r >> 16);
}

// max over the 16-lane group (lanes sharing lane>>4), DPP only (no LDS pipe).
__device__ inline float dpp_max16(float x) {
  union { float f; int i; } v, t;
  v.f = x;
  t.i = __builtin_amdgcn_update_dpp(0, v.i, 0xB1, 0xF, 0xF, true);  // quad_perm [1,0,3,2] = xor1
  v.f = fmaxf(v.f, t.f);
  t.i = __builtin_amdgcn_update_dpp(0, v.i, 0x4E, 0xF, 0xF, true);  // quad_perm [2,3,0,1] = xor2
  v.f = fmaxf(v.f, t.f);
  t.i = __builtin_amdgcn_update_dpp(0, v.i, 0x124, 0xF, 0xF, true); // row_ror:4
  v.f = fmaxf(v.f, t.f);
  t.i = __builtin_amdgcn_update_dpp(0, v.i, 0x128, 0xF, 0xF, true); // row_ror:8
  v.f = fmaxf(v.f, t.f);
  return v.f;
}
__device__ inline float dpp_sum16(float x) {
  union { float f; int i; } v, t;
  v.f = x;
  t.i = __builtin_amdgcn_update_dpp(0, v.i, 0xB1, 0xF, 0xF, true);
  v.f += t.f;
  t.i = __builtin_amdgcn_update_dpp(0, v.i, 0x4E, 0xF, 0xF, true);
  v.f += t.f;
  t.i = __builtin_amdgcn_update_dpp(0, v.i, 0x124, 0xF, 0xF, true);
  v.f += t.f;
  t.i = __builtin_amdgcn_update_dpp(0, v.i, 0x128, 0xF, 0xF, true);
  v.f += t.f;
  return v.f;
}

// ---------- kernel 1: W [1024][128] f32 (x3) -> Wt [3][128][1024] bf16 ----------
__global__ __launch_bounds__(256) void wt_kernel(const float* __restrict__ Wq,
    const float* __restrict__ Wk, const float* __restrict__ Wv,
    ushort* __restrict__ Wt) {
  int bid = blockIdx.x;               // 384 = 3 mats * 4 h-tiles * 32 e-tiles
  int mat = bid >> 7;
  int rem = bid & 127;
  int ht = rem >> 5, et = rem & 31;
  const float* W = mat == 0 ? Wq : (mat == 1 ? Wk : Wv);
  int e0 = et * 32, h0 = ht * 32;
  __shared__ float tl[32][33];
  int t = threadIdx.x;
  int r = t >> 3, c = (t & 7) << 2;
  const float4 f = *(const float4*)(W + (size_t)(e0 + r) * H_ + h0 + c);
  tl[r][c] = f.x; tl[r][c+1] = f.y; tl[r][c+2] = f.z; tl[r][c+3] = f.w;
  __syncthreads();
  ushort4 o;
  o.x = f2bf(tl[c+0][r]); o.y = f2bf(tl[c+1][r]);
  o.z = f2bf(tl[c+2][r]); o.w = f2bf(tl[c+3][r]);
  *(ushort4*)(Wt + ((size_t)mat*H_ + h0 + r) * E_ + e0 + c) = o;
}

// ---------- kernel 2: fused QKV projection GEMM, ping-pong double-buffered ----------
// x [16384][1024] f32 @ Wt[3][128][1024] bf16 -> q,k [16384][128] bf16, vT [4][128][4096] bf16
__global__ __launch_bounds__(256) void qkv_gemm(const float* __restrict__ x,
    const ushort* __restrict__ Wt, ushort* __restrict__ qo,
    ushort* __restrict__ ko, ushort* __restrict__ vTo) {
  const int m0 = blockIdx.x * 32;
  const int tid = threadIdx.x;
  const int wave = tid >> 6, lane = tid & 63;
  const int col = lane & 15, quad = lane >> 4;
  __shared__ ushort xa[2][32 * 72];       // ping-pong, 32 rows x BK=64, stride 72
  f32x4 acc[2][6];
  #pragma unroll
  for (int i = 0; i < 2; i++)
    #pragma unroll
    for (int j = 0; j < 6; j++) acc[i][j] = (f32x4){0.f,0.f,0.f,0.f};

  const int sr = tid >> 3;                // staging row 0..31
  const int sc = (tid & 7) << 3;          // 0..56 step 8
  const float* xsrc = x + (size_t)(m0 + sr) * E_ + sc;

  // prologue: stage k-block 0 into buffer 0
  {
    float4 f0 = *(const float4*)(xsrc + 0);
    float4 f1 = *(const float4*)(xsrc + 4);
    alignas(16) ushort us[8];
    us[0]=f2bf(f0.x); us[1]=f2bf(f0.y); us[2]=f2bf(f0.z); us[3]=f2bf(f0.w);
    us[4]=f2bf(f1.x); us[5]=f2bf(f1.y); us[6]=f2bf(f1.z); us[7]=f2bf(f1.w);
    *(uint4*)(&xa[0][sr*72+sc]) = *(uint4*)&us[0];
  }
  __syncthreads();

  for (int it = 0; it < 16; it++) {
    // prefetch next k-block into registers (clamped on last iter; store unused)
    int nit = it + 1 < 16 ? it + 1 : it;
    float4 g0 = *(const float4*)(xsrc + nit*64 + 0);
    float4 g1 = *(const float4*)(xsrc + nit*64 + 4);

    const ushort* xcur = &xa[it & 1][0];
    const int kb = it * 64;
    #pragma unroll
    for (int kc = 0; kc < 2; kc++) {
      bf16x8 af[2];
      #pragma unroll
      for (int mt = 0; mt < 2; mt++)
        af[mt] = *(const bf16x8*)(xcur + (mt*16 + col)*72 + kc*32 + quad*8);
      #pragma unroll
      for (int nt = 0; nt < 6; nt++) {
        int n = wave*96 + nt*16 + col;    // 0..383
        bf16x8 bfv = *(const bf16x8*)(Wt + ((size_t)(n >> 7) * H_ + (n & 127)) * E_
                                      + kb + kc*32 + quad*8);
        #pragma unroll
        for (int mt = 0; mt < 2; mt++)
          acc[mt][nt] = __builtin_amdgcn_mfma_f32_16x16x32_bf16(af[mt], bfv, acc[mt][nt], 0, 0, 0);
      }
    }
    // stage prefetched block into the other buffer
    alignas(16) ushort us[8];
    us[0]=f2bf(g0.x); us[1]=f2bf(g0.y); us[2]=f2bf(g0.z); us[3]=f2bf(g0.w);
    us[4]=f2bf(g1.x); us[5]=f2bf(g1.y); us[6]=f2bf(g1.z); us[7]=f2bf(g1.w);
    *(uint4*)(&xa[(it + 1) & 1][sr*72+sc]) = *(uint4*)&us[0];
    __syncthreads();
  }

  #pragma unroll
  for (int nt = 0; nt < 6; nt++) {
    int n = wave*96 + nt*16 + col;
    int mat = n >> 7, nw = n & 127;
    #pragma unroll
    for (int mt = 0; mt < 2; mt++) {
      int row0 = m0 + mt*16 + quad*4;
      #pragma unroll
      for (int r = 0; r < 4; r++) {
        int row = row0 + r;
        ushort val = f2bf(acc[mt][nt][r]);
        if (mat == 2) {   // V: write transposed vT[b][h][s]
          int bb = row >> 12, s = row & 4095;
          vTo[((size_t)bb * H_ + nw) * S_ + s] = val;
        } else {
          ushort* dst = (mat == 0 ? qo : ko);
          dst[(size_t)row * H_ + nw] = val;
        }
      }
    }
  }
}

// ---------- kernel 3: causal flash attention, split-K, pipelined ----------
// grid (c=8, t=64, b=4); chunk = keys [512c, 512c+512); invalid if t < 8c.
#define CHUNK_ 512
__global__ __launch_bounds__(256) void flash_kernel(const ushort* __restrict__ q,
    const ushort* __restrict__ k, const ushort* __restrict__ vT,
    float* __restrict__ Opart, float* __restrict__ ml) {
  const float SL2E = 0.08838834764831845f * 1.44269504088896340736f; // scale*log2(e)
  int c = blockIdx.x, tile = blockIdx.y, b = blockIdx.z;
  if (tile < 8 * c) return;
  int a = tile >> 3, rr = tile & 7;
  int slot = b * 288 + (a + 1) * (4 * a + rr) + c;

  int wave = threadIdx.x >> 6, lane = threadIdx.x & 63;
  int col = lane & 15, quad = lane >> 4;
  int q0 = tile * 64 + wave * 16;
  const ushort* qb = q + (size_t)b * S_ * H_;
  const ushort* kbp = k + (size_t)b * S_ * H_;
  const ushort* vb = vT + (size_t)b * H_ * S_;

  __shared__ ushort plds[4][16 * 40];
  ushort* pw = &plds[wave][0];

  bf16x8 qf[4];
  const ushort* qptr = qb + (size_t)(q0 + col) * H_ + quad * 8;
  #pragma unroll
  for (int kc = 0; kc < 4; kc++) qf[kc] = *(const bf16x8*)(qptr + kc * 32);

  f32x4 O[8];
  #pragma unroll
  for (int d = 0; d < 8; d++) O[d] = (f32x4){0.f,0.f,0.f,0.f};
  float m_i[4], l_i[4];
  #pragma unroll
  for (int r = 0; r < 4; r++) { m_i[r] = -1e30f; l_i[r] = 0.f; }

  const int c0 = c * CHUNK_;
  const int kend = min(c0 + CHUNK_, q0 + 16);
  const int nblk = (kend - c0 + 31) >> 5;

  const ushort* kbase = kbp + ((size_t)c0 + col) * H_ + quad * 8;
  const ushort* vbase = vb + c0 + quad * 8 + (size_t)col * S_;

  // preload K block 0 into registers
  bf16x8 kf0[4], kf1[4];
  #pragma unroll
  for (int kc = 0; kc < 4; kc++) {
    kf0[kc] = *(const bf16x8*)(kbase + kc * 32);
    kf1[kc] = *(const bf16x8*)(kbase + 16 * H_ + kc * 32);
  }

  for (int ib = 0; ib < nblk; ib++) {
    const int kb0 = c0 + ib * 32;
    // V loads for this block (independent of softmax — issue early)
    bf16x8 vf[8];
    #pragma unroll
    for (int d = 0; d < 8; d++)
      vf[d] = *(const bf16x8*)(vbase + ib * 32 + (size_t)(d * 16) * S_);

    // scores from pre-loaded K registers
    f32x4 sc0 = (f32x4){0.f,0.f,0.f,0.f}, sc1 = (f32x4){0.f,0.f,0.f,0.f};
    #pragma unroll
    for (int kc = 0; kc < 4; kc++) {
      sc0 = __builtin_amdgcn_mfma_f32_16x16x32_bf16(qf[kc], kf0[kc], sc0, 0, 0, 0);
      sc1 = __builtin_amdgcn_mfma_f32_16x16x32_bf16(qf[kc], kf1[kc], sc1, 0, 0, 0);
    }

    // prefetch next K block (clamped; redundant loads on last iter are harmless)
    {
      int ibn = ib + 1 < nblk ? ib + 1 : ib;
      const ushort* knp = kbase + (size_t)ibn * 32 * H_;
      #pragma unroll
      for (int kc = 0; kc < 4; kc++) {
        kf0[kc] = *(const bf16x8*)(knp + kc * 32);
        kf1[kc] = *(const bf16x8*)(knp + 16 * H_ + kc * 32);
      }
    }

    float s0[4], s1[4];
    #pragma unroll
    for (int r = 0; r < 4; r++) { s0[r] = sc0[r]; s1[r] = sc1[r]; }  // raw domain
    if (kb0 + 31 > q0) {
      #pragma unroll
      for (int r = 0; r < 4; r++) {
        int row = q0 + quad*4 + r;
        if (kb0 + col > row)      s0[r] = -1e30f;
        if (kb0 + 16 + col > row) s1[r] = -1e30f;
      }
    }
    float alpha[4], p0[4], p1[4];
    #pragma unroll
    for (int r = 0; r < 4; r++) {
      float cm = dpp_max16(fmaxf(s0[r], s1[r]));
      float mn = fmaxf(m_i[r], cm);
      alpha[r] = exp2f((m_i[r] - mn) * SL2E);
      m_i[r] = mn;
      p0[r] = exp2f((s0[r] - mn) * SL2E);
      p1[r] = exp2f((s1[r] - mn) * SL2E);
      float rs = dpp_sum16(p0[r] + p1[r]);
      l_i[r] = l_i[r] * alpha[r] + rs;
    }
    #pragma unroll
    for (int d = 0; d < 8; d++) {
      #pragma unroll
      for (int r = 0; r < 4; r++) O[d][r] *= alpha[r];
    }
    // P: C-layout -> LDS -> A-layout (bf16); per-wave region, no barrier needed
    #pragma unroll
    for (int r = 0; r < 4; r++) {
      pw[(quad*4 + r)*40 + col]      = f2bf(p0[r]);
      pw[(quad*4 + r)*40 + 16 + col] = f2bf(p1[r]);
    }
    bf16x8 pf = *(const bf16x8*)(pw + col*40 + quad*8);
    #pragma unroll
    for (int d = 0; d < 8; d++)
      O[d] = __builtin_amdgcn_mfma_f32_16x16x32_bf16(pf, vf[d], O[d], 0, 0, 0);
  }

  float* Op = Opart + (size_t)slot * (64 * 128);
  #pragma unroll
  for (int d = 0; d < 8; d++) {
    #pragma unroll
    for (int r = 0; r < 4; r++)
      Op[(wave*16 + quad*4 + r) * 128 + d*16 + col] = O[d][r];
  }
  if (col == 0) {
    #pragma unroll
    for (int r = 0; r < 4; r++) {
      int rl = wave*16 + quad*4 + r;
      ml[(size_t)slot*128 + rl*2]     = m_i[r];
      ml[(size_t)slot*128 + rl*2 + 1] = l_i[r];
    }
  }
}

// ---------- kernel 4: combine split-K partials ----------
__global__ __launch_bounds__(256) void combine_kernel(const float* __restrict__ Opart,
    const float* __restrict__ ml, float* __restrict__ out) {
  const float SL2E = 0.08838834764831845f * 1.44269504088896340736f;
  int tile = blockIdx.x, b = blockIdx.y;
  int a = tile >> 3, rr = tile & 7;
  int nc = a + 1;
  int base = b * 288 + (a + 1) * (4 * a + rr);
  int tid = threadIdx.x;
  int row = tid >> 2;                       // 0..63
  int cs = (tid & 3) * 4;
  float m_c[8], l_c[8];
  float mstar = -1e30f;
  for (int ci = 0; ci < nc; ci++) {
    m_c[ci] = ml[(size_t)(base + ci) * 128 + row * 2];
    l_c[ci] = ml[(size_t)(base + ci) * 128 + row * 2 + 1];
    mstar = fmaxf(mstar, m_c[ci]);
  }
  float denom = 0.f;
  float w_c[8];
  for (int ci = 0; ci < nc; ci++) {
    w_c[ci] = exp2f((m_c[ci] - mstar) * SL2E);
    denom += w_c[ci] * l_c[ci];
  }
  float inv = 1.f / denom;
  f32x4 acc[8];
  #pragma unroll
  for (int i = 0; i < 8; i++) acc[i] = (f32x4){0.f,0.f,0.f,0.f};
  for (int ci = 0; ci < nc; ci++) {
    const float* Op = Opart + (size_t)(base + ci) * (64 * 128) + row * 128;
    float w = w_c[ci];
    #pragma unroll
    for (int i = 0; i < 8; i++) {
      f32x4 v = *(const f32x4*)(Op + cs + i * 16);
      acc[i] += w * v;
    }
  }
  float* o = out + ((size_t)(b * S_) + tile * 64 + row) * H_;
  #pragma unroll
  for (int i = 0; i < 8; i++) {
    f32x4 v = acc[i] * inv;
    *(f32x4*)(o + cs + i * 16) = v;
  }
}

extern "C" void kernel_launch(void* const* d_in, const int* in_sizes, int n_in,
                              void* d_out, int out_size, void* d_ws, size_t ws_size,
                              hipStream_t stream) {
  (void)in_sizes; (void)n_in; (void)out_size; (void)ws_size;
  const float* x  = (const float*)d_in[0];
  const float* Wq = (const float*)d_in[1];
  const float* Wk = (const float*)d_in[2];
  const float* Wv = (const float*)d_in[3];
  float* out = (float*)d_out;
  char* ws = (char*)d_ws;
  ushort* Wt = (ushort*)ws;                       // 786,432 B
  ushort* qb = (ushort*)(ws + 786432);            // 4 MB each
  ushort* kb = qb + (size_t)M_ * H_;
  ushort* vT = kb + (size_t)M_ * H_;
  float* Opart = (float*)(ws + 786432 + 3 * (size_t)M_ * H_ * 2);  // 1152*32KB
  float* ml = Opart + (size_t)1152 * 64 * 128;                     // 1152*512B

  hipLaunchKernelGGL(wt_kernel,   dim3(384), dim3(256), 0, stream, Wq, Wk, Wv, Wt);
  hipLaunchKernelGGL(qkv_gemm,    dim3(512), dim3(256), 0, stream, x, Wt, qb, kb, vT);
  hipLaunchKernelGGL(flash_kernel,dim3(8, 64, 4), dim3(256), 0, stream, qb, kb, vT, Opart, ml);
  hipLaunchKernelGGL(combine_kernel, dim3(64, 4), dim3(256), 0, stream, Opart, ml, out);
}

// Round 4
// 390.405 us; speedup vs baseline: 1.1061x; 1.0363x over previous
//
#include <hip/hip_runtime.h>

#define B_ 4
#define S_ 4096
#define E_ 1024
#define H_ 128
#define M_ (B_*S_)   // 16384

typedef __attribute__((ext_vector_type(8))) short bf16x8;
typedef __attribute__((ext_vector_type(4))) float f32x4;

__device__ inline ushort f2bf(float f) {
  union { float f; unsigned u; } v; v.f = f;
  unsigned r = v.u + 0x7fffu + ((v.u >> 16) & 1u);   // RNE
  return (ushort)(r >> 16);
}

__device__ inline float bpermf(int addr, float x) {
  union { float f; int i; } v; v.f = x;
  v.i = __builtin_amdgcn_ds_bpermute(addr, v.i);
  return v.f;
}

// ---------- kernel 1: W [1024][128] f32 (x3) -> Wt [3][128][1024] bf16 ----------
__global__ __launch_bounds__(256) void wt_kernel(const float* __restrict__ Wq,
    const float* __restrict__ Wk, const float* __restrict__ Wv,
    ushort* __restrict__ Wt) {
  int bid = blockIdx.x;               // 384 = 3 mats * 4 h-tiles * 32 e-tiles
  int mat = bid >> 7;
  int rem = bid & 127;
  int ht = rem >> 5, et = rem & 31;
  const float* W = mat == 0 ? Wq : (mat == 1 ? Wk : Wv);
  int e0 = et * 32, h0 = ht * 32;
  __shared__ float tl[32][33];
  int t = threadIdx.x;
  int r = t >> 3, c = (t & 7) << 2;
  const float4 f = *(const float4*)(W + (size_t)(e0 + r) * H_ + h0 + c);
  tl[r][c] = f.x; tl[r][c+1] = f.y; tl[r][c+2] = f.z; tl[r][c+3] = f.w;
  __syncthreads();
  ushort4 o;
  o.x = f2bf(tl[c+0][r]); o.y = f2bf(tl[c+1][r]);
  o.z = f2bf(tl[c+2][r]); o.w = f2bf(tl[c+3][r]);
  *(ushort4*)(Wt + ((size_t)mat*H_ + h0 + r) * E_ + e0 + c) = o;
}

// ---------- kernel 2: fused QKV projection GEMM, N-split x2, double-buffered ----------
// x [16384][1024] f32 @ Wt[3][128][1024] bf16 -> q,k [16384][128] bf16, vT [4][128][4096] bf16
__global__ __launch_bounds__(256) void qkv_gemm(const float* __restrict__ x,
    const ushort* __restrict__ Wt, ushort* __restrict__ qo,
    ushort* __restrict__ ko, ushort* __restrict__ vTo) {
  const int m0 = blockIdx.x * 32;
  const int nhalf = blockIdx.y * 192;       // N-split: this WG does cols [nhalf, nhalf+192)
  const int tid = threadIdx.x;
  const int wave = tid >> 6, lane = tid & 63;
  const int col = lane & 15, quad = lane >> 4;
  __shared__ ushort xa[2][32 * 72];
  f32x4 acc[2][3];
  #pragma unroll
  for (int i = 0; i < 2; i++)
    #pragma unroll
    for (int j = 0; j < 3; j++) acc[i][j] = (f32x4){0.f,0.f,0.f,0.f};

  const int sr = tid >> 3;                // staging row 0..31
  const int sc = (tid & 7) << 3;          // 0..56 step 8
  const float* xsrc = x + (size_t)(m0 + sr) * E_ + sc;

  {
    float4 f0 = *(const float4*)(xsrc + 0);
    float4 f1 = *(const float4*)(xsrc + 4);
    alignas(16) ushort us[8];
    us[0]=f2bf(f0.x); us[1]=f2bf(f0.y); us[2]=f2bf(f0.z); us[3]=f2bf(f0.w);
    us[4]=f2bf(f1.x); us[5]=f2bf(f1.y); us[6]=f2bf(f1.z); us[7]=f2bf(f1.w);
    *(uint4*)(&xa[0][sr*72+sc]) = *(uint4*)&us[0];
  }
  __syncthreads();

  for (int it = 0; it < 16; it++) {
    int nit = it + 1 < 16 ? it + 1 : it;
    float4 g0 = *(const float4*)(xsrc + nit*64 + 0);
    float4 g1 = *(const float4*)(xsrc + nit*64 + 4);

    const ushort* xcur = &xa[it & 1][0];
    const int kb = it * 64;
    #pragma unroll
    for (int kc = 0; kc < 2; kc++) {
      bf16x8 af[2];
      #pragma unroll
      for (int mt = 0; mt < 2; mt++)
        af[mt] = *(const bf16x8*)(xcur + (mt*16 + col)*72 + kc*32 + quad*8);
      #pragma unroll
      for (int nt = 0; nt < 3; nt++) {
        int n = nhalf + wave*48 + nt*16 + col;   // 0..383
        bf16x8 bfv = *(const bf16x8*)(Wt + ((size_t)(n >> 7) * H_ + (n & 127)) * E_
                                      + kb + kc*32 + quad*8);
        #pragma unroll
        for (int mt = 0; mt < 2; mt++)
          acc[mt][nt] = __builtin_amdgcn_mfma_f32_16x16x32_bf16(af[mt], bfv, acc[mt][nt], 0, 0, 0);
      }
    }
    alignas(16) ushort us[8];
    us[0]=f2bf(g0.x); us[1]=f2bf(g0.y); us[2]=f2bf(g0.z); us[3]=f2bf(g0.w);
    us[4]=f2bf(g1.x); us[5]=f2bf(g1.y); us[6]=f2bf(g1.z); us[7]=f2bf(g1.w);
    *(uint4*)(&xa[(it + 1) & 1][sr*72+sc]) = *(uint4*)&us[0];
    __syncthreads();
  }

  #pragma unroll
  for (int nt = 0; nt < 3; nt++) {
    int n = nhalf + wave*48 + nt*16 + col;
    int mat = n >> 7, nw = n & 127;
    #pragma unroll
    for (int mt = 0; mt < 2; mt++) {
      int row0 = m0 + mt*16 + quad*4;
      #pragma unroll
      for (int r = 0; r < 4; r++) {
        int row = row0 + r;
        ushort val = f2bf(acc[mt][nt][r]);
        if (mat == 2) {   // V: write transposed vT[b][h][s]
          int bb = row >> 12, s = row & 4095;
          vTo[((size_t)bb * H_ + nw) * S_ + s] = val;
        } else {
          ushort* dst = (mat == 0 ? qo : ko);
          dst[(size_t)row * H_ + nw] = val;
        }
      }
    }
  }
}

// ---------- kernel 3: causal flash attention, split-K, 1-wave WGs, S^T softmax ----------
// grid (c=8, t4=256 (reversed), b=4); WG = 64 threads = 1 wave, owns 16 q-rows x 512-key chunk.
#define CHUNK_ 512
__global__ __launch_bounds__(64, 3) void flash_kernel(const ushort* __restrict__ q,
    const ushort* __restrict__ k, const ushort* __restrict__ vT,
    float* __restrict__ Opart, float* __restrict__ ml) {
  const float SL2E = 0.08838834764831845f * 1.44269504088896340736f; // scale*log2(e)
  int c = blockIdx.x;
  int t4 = 255 - (int)blockIdx.y;             // heavy tiles dispatch first
  int b = blockIdx.z;
  int tile = t4 >> 2, wave = t4 & 3;
  if (tile < 8 * c) return;
  int a = tile >> 3, rr = tile & 7;
  int slot = b * 288 + (a + 1) * (4 * a + rr) + c;

  int lane = threadIdx.x;
  int col = lane & 15, quad = lane >> 4;
  int xa16 = ((lane ^ 16) << 2);
  int xa32 = ((lane ^ 32) << 2);
  int q0 = tile * 64 + wave * 16;
  const ushort* qb = q + (size_t)b * S_ * H_;
  const ushort* kbp = k + (size_t)b * S_ * H_;
  const ushort* vb = vT + (size_t)b * H_ * S_;

  __shared__ ushort pl[16 * 40];              // P rows [q=col][k 0..31], stride 40 (80 B)

  bf16x8 qf[4];                               // Q[q0+col][quad*8 + kc*32 + j]
  const ushort* qptr = qb + (size_t)(q0 + col) * H_ + quad * 8;
  #pragma unroll
  for (int kc = 0; kc < 4; kc++) qf[kc] = *(const bf16x8*)(qptr + kc * 32);

  f32x4 O[8];                                 // O^T[dblk*16+quad*4+r][q0+col]
  #pragma unroll
  for (int d = 0; d < 8; d++) O[d] = (f32x4){0.f,0.f,0.f,0.f};
  float m_i = -1e30f, l_i = 0.f;              // per-lane = per-query scalars

  const int c0 = c * CHUNK_;
  const int kend = min(c0 + CHUNK_, q0 + 16);
  const int nblk = (kend - c0 + 31) >> 5;

  const ushort* kbase = kbp + ((size_t)c0 + col) * H_ + quad * 8;
  const ushort* vbase = vb + (size_t)col * S_ + c0 + quad * 8;

  for (int ib = 0; ib < nblk; ib++) {
    const int kb0 = c0 + ib * 32;
    // K fragments: K[kb0+col][quad*8+kc*32+j] (A of S^T-mfma)
    const ushort* kp = kbase + (size_t)ib * 32 * H_;
    bf16x8 kf0[4], kf1[4];
    #pragma unroll
    for (int kc = 0; kc < 4; kc++) {
      kf0[kc] = *(const bf16x8*)(kp + kc * 32);
      kf1[kc] = *(const bf16x8*)(kp + 16 * H_ + kc * 32);
    }
    // V fragments: V^T[dblk*16+col][kb0+quad*8+j] (A of PV-mfma) — independent, issue early
    bf16x8 vf[8];
    #pragma unroll
    for (int d = 0; d < 8; d++)
      vf[d] = *(const bf16x8*)(vbase + ib * 32 + (size_t)(d * 16) * S_);

    // S^T = K Q^T: lane holds S^T[kb0(+16)+quad*4+r][q0+col]
    f32x4 st0 = (f32x4){0.f,0.f,0.f,0.f}, st1 = (f32x4){0.f,0.f,0.f,0.f};
    #pragma unroll
    for (int kc = 0; kc < 4; kc++) {
      st0 = __builtin_amdgcn_mfma_f32_16x16x32_bf16(kf0[kc], qf[kc], st0, 0, 0, 0);
      st1 = __builtin_amdgcn_mfma_f32_16x16x32_bf16(kf1[kc], qf[kc], st1, 0, 0, 0);
    }
    float s[8];
    #pragma unroll
    for (int r = 0; r < 4; r++) { s[r] = st0[r]; s[4+r] = st1[r]; }
    if (kb0 + 31 > q0) {                      // causal: mask key > query
      #pragma unroll
      for (int r = 0; r < 4; r++) {
        if (kb0 + quad*4 + r      > q0 + col) s[r]   = -1e30f;
        if (kb0 + 16 + quad*4 + r > q0 + col) s[4+r] = -1e30f;
      }
    }
    // column (=query) max: 7 in-lane + butterfly across quads
    float cm = s[0];
    #pragma unroll
    for (int j = 1; j < 8; j++) cm = fmaxf(cm, s[j]);
    cm = fmaxf(cm, bpermf(xa16, cm));
    cm = fmaxf(cm, bpermf(xa32, cm));
    float mn = fmaxf(m_i, cm);
    float alpha = exp2f((m_i - mn) * SL2E);
    m_i = mn;
    float p[8], rs = 0.f;
    #pragma unroll
    for (int j = 0; j < 8; j++) { p[j] = exp2f((s[j] - mn) * SL2E); rs += p[j]; }
    rs += bpermf(xa16, rs);
    rs += bpermf(xa32, rs);
    l_i = l_i * alpha + rs;
    #pragma unroll
    for (int d = 0; d < 8; d++) O[d] *= alpha;
    // P^T (C-layout) -> LDS rows [q][k] -> B-fragment for PV
    {
      unsigned* pq = (unsigned*)(pl + col * 40);
      unsigned w0 = (unsigned)f2bf(p[0]) | ((unsigned)f2bf(p[1]) << 16);
      unsigned w1 = (unsigned)f2bf(p[2]) | ((unsigned)f2bf(p[3]) << 16);
      unsigned w2 = (unsigned)f2bf(p[4]) | ((unsigned)f2bf(p[5]) << 16);
      unsigned w3 = (unsigned)f2bf(p[6]) | ((unsigned)f2bf(p[7]) << 16);
      pq[quad*2]       = w0;   // keys quad*4+0,1
      pq[quad*2 + 1]   = w1;   // keys quad*4+2,3
      pq[8 + quad*2]     = w2; // keys 16+quad*4+0,1
      pq[8 + quad*2 + 1] = w3; // keys 16+quad*4+2,3
    }
    bf16x8 pf = *(const bf16x8*)(pl + col * 40 + quad * 8);  // P[q=col][quad*8+j]
    #pragma unroll
    for (int d = 0; d < 8; d++)
      O[d] = __builtin_amdgcn_mfma_f32_16x16x32_bf16(vf[d], pf, O[d], 0, 0, 0);
  }

  // epilogue: O^T lane regs are contiguous in d -> coalesced dwordx4 stores
  float* Op = Opart + (size_t)slot * (64 * 128) + (size_t)(wave*16 + col) * 128 + quad * 4;
  #pragma unroll
  for (int d = 0; d < 8; d++)
    *(f32x4*)(Op + d * 16) = O[d];
  if (quad == 0) {
    float2* mlp = (float2*)(ml + (size_t)slot * 128 + (size_t)(wave*16 + col) * 2);
    *mlp = make_float2(m_i, l_i);
  }
}

// ---------- kernel 4: combine split-K partials ----------
__global__ __launch_bounds__(256) void combine_kernel(const float* __restrict__ Opart,
    const float* __restrict__ ml, float* __restrict__ out) {
  const float SL2E = 0.08838834764831845f * 1.44269504088896340736f;
  int tile = blockIdx.x, b = blockIdx.y;
  int a = tile >> 3, rr = tile & 7;
  int nc = a + 1;
  int base = b * 288 + (a + 1) * (4 * a + rr);
  int tid = threadIdx.x;
  int row = tid >> 2;                       // 0..63
  int cs = (tid & 3) * 4;
  float m_c[8], l_c[8];
  float mstar = -1e30f;
  for (int ci = 0; ci < nc; ci++) {
    m_c[ci] = ml[(size_t)(base + ci) * 128 + row * 2];
    l_c[ci] = ml[(size_t)(base + ci) * 128 + row * 2 + 1];
    mstar = fmaxf(mstar, m_c[ci]);
  }
  float denom = 0.f;
  float w_c[8];
  for (int ci = 0; ci < nc; ci++) {
    w_c[ci] = exp2f((m_c[ci] - mstar) * SL2E);
    denom += w_c[ci] * l_c[ci];
  }
  float inv = 1.f / denom;
  f32x4 acc[8];
  #pragma unroll
  for (int i = 0; i < 8; i++) acc[i] = (f32x4){0.f,0.f,0.f,0.f};
  for (int ci = 0; ci < nc; ci++) {
    const float* Op = Opart + (size_t)(base + ci) * (64 * 128) + row * 128;
    float w = w_c[ci];
    #pragma unroll
    for (int i = 0; i < 8; i++) {
      f32x4 v = *(const f32x4*)(Op + cs + i * 16);
      acc[i] += w * v;
    }
  }
  float* o = out + ((size_t)(b * S_) + tile * 64 + row) * H_;
  #pragma unroll
  for (int i = 0; i < 8; i++) {
    f32x4 v = acc[i] * inv;
    *(f32x4*)(o + cs + i * 16) = v;
  }
}

extern "C" void kernel_launch(void* const* d_in, const int* in_sizes, int n_in,
                              void* d_out, int out_size, void* d_ws, size_t ws_size,
                              hipStream_t stream) {
  (void)in_sizes; (void)n_in; (void)out_size; (void)ws_size;
  const float* x  = (const float*)d_in[0];
  const float* Wq = (const float*)d_in[1];
  const float* Wk = (const float*)d_in[2];
  const float* Wv = (const float*)d_in[3];
  float* out = (float*)d_out;
  char* ws = (char*)d_ws;
  ushort* Wt = (ushort*)ws;                       // 786,432 B
  ushort* qb = (ushort*)(ws + 786432);            // 4 MB each
  ushort* kb = qb + (size_t)M_ * H_;
  ushort* vT = kb + (size_t)M_ * H_;
  float* Opart = (float*)(ws + 786432 + 3 * (size_t)M_ * H_ * 2);  // 1152*32KB
  float* ml = Opart + (size_t)1152 * 64 * 128;                     // 1152*512B

  hipLaunchKernelGGL(wt_kernel,   dim3(384), dim3(256), 0, stream, Wq, Wk, Wv, Wt);
  hipLaunchKernelGGL(qkv_gemm,    dim3(512, 2), dim3(256), 0, stream, x, Wt, qb, kb, vT);
  hipLaunchKernelGGL(flash_kernel,dim3(8, 256, 4), dim3(64), 0, stream, qb, kb, vT, Opart, ml);
  hipLaunchKernelGGL(combine_kernel, dim3(64, 4), dim3(256), 0, stream, Opart, ml, out);
}

// Round 5
// 306.362 us; speedup vs baseline: 1.4095x; 1.2743x over previous
//
#include <hip/hip_runtime.h>

#define B_ 4
#define S_ 4096
#define E_ 1024
#define H_ 128
#define M_ (B_*S_)   // 16384

typedef __attribute__((ext_vector_type(8))) short bf16x8;
typedef __attribute__((ext_vector_type(4))) float f32x4;

__device__ inline ushort f2bf(float f) {
  union { float f; unsigned u; } v; v.f = f;
  unsigned r = v.u + 0x7fffu + ((v.u >> 16) & 1u);   // RNE
  return (ushort)(r >> 16);
}

__device__ inline float bpermf(int addr, float x) {
  union { float f; int i; } v; v.f = x;
  v.i = __builtin_amdgcn_ds_bpermute(addr, v.i);
  return v.f;
}

// ---------- kernel 1: W [1024][128] f32 (x3) -> Wt [3][128][1024] bf16 ----------
__global__ __launch_bounds__(256) void wt_kernel(const float* __restrict__ Wq,
    const float* __restrict__ Wk, const float* __restrict__ Wv,
    ushort* __restrict__ Wt) {
  int bid = blockIdx.x;               // 384 = 3 mats * 4 h-tiles * 32 e-tiles
  int mat = bid >> 7;
  int rem = bid & 127;
  int ht = rem >> 5, et = rem & 31;
  const float* W = mat == 0 ? Wq : (mat == 1 ? Wk : Wv);
  int e0 = et * 32, h0 = ht * 32;
  __shared__ float tl[32][33];
  int t = threadIdx.x;
  int r = t >> 3, c = (t & 7) << 2;
  const float4 f = *(const float4*)(W + (size_t)(e0 + r) * H_ + h0 + c);
  tl[r][c] = f.x; tl[r][c+1] = f.y; tl[r][c+2] = f.z; tl[r][c+3] = f.w;
  __syncthreads();
  ushort4 o;
  o.x = f2bf(tl[c+0][r]); o.y = f2bf(tl[c+1][r]);
  o.z = f2bf(tl[c+2][r]); o.w = f2bf(tl[c+3][r]);
  *(ushort4*)(Wt + ((size_t)mat*H_ + h0 + r) * E_ + e0 + c) = o;
}

// ---------- kernel 2: fused QKV projection GEMM, N-split x2, dbuf + B-prefetch ----------
__global__ __launch_bounds__(256, 4) void qkv_gemm(const float* __restrict__ x,
    const ushort* __restrict__ Wt, ushort* __restrict__ qo,
    ushort* __restrict__ ko, ushort* __restrict__ vTo) {
  const int m0 = blockIdx.x * 32;
  const int nhalf = blockIdx.y * 192;
  const int tid = threadIdx.x;
  const int wave = tid >> 6, lane = tid & 63;
  const int col = lane & 15, quad = lane >> 4;
  __shared__ ushort xa[2][32 * 72];
  f32x4 acc[2][3];
  #pragma unroll
  for (int i = 0; i < 2; i++)
    #pragma unroll
    for (int j = 0; j < 3; j++) acc[i][j] = (f32x4){0.f,0.f,0.f,0.f};

  const int sr = tid >> 3;
  const int sc = (tid & 7) << 3;
  const float* xsrc = x + (size_t)(m0 + sr) * E_ + sc;

  // per-nt Wt base pointers; fragment for step s (=it*2+kc) at +s*32
  const ushort* Wtp[3];
  #pragma unroll
  for (int nt = 0; nt < 3; nt++) {
    int n = nhalf + wave*48 + nt*16 + col;
    Wtp[nt] = Wt + ((size_t)(n >> 7) * H_ + (n & 127)) * E_ + quad * 8;
  }
  bf16x8 bcur[3], bnx[3];
  #pragma unroll
  for (int nt = 0; nt < 3; nt++) bcur[nt] = *(const bf16x8*)(Wtp[nt]);

  {
    float4 f0 = *(const float4*)(xsrc + 0);
    float4 f1 = *(const float4*)(xsrc + 4);
    alignas(16) ushort us[8];
    us[0]=f2bf(f0.x); us[1]=f2bf(f0.y); us[2]=f2bf(f0.z); us[3]=f2bf(f0.w);
    us[4]=f2bf(f1.x); us[5]=f2bf(f1.y); us[6]=f2bf(f1.z); us[7]=f2bf(f1.w);
    *(uint4*)(&xa[0][sr*72+sc]) = *(uint4*)&us[0];
  }
  __syncthreads();

  for (int it = 0; it < 16; it++) {
    int nit = it + 1 < 16 ? it + 1 : it;
    float4 g0 = *(const float4*)(xsrc + nit*64 + 0);
    float4 g1 = *(const float4*)(xsrc + nit*64 + 4);

    const ushort* xcur = &xa[it & 1][0];
    #pragma unroll
    for (int kc = 0; kc < 2; kc++) {
      int s = it*2 + kc;
      int sn = s + 1 < 32 ? s + 1 : s;
      #pragma unroll
      for (int nt = 0; nt < 3; nt++)
        bnx[nt] = *(const bf16x8*)(Wtp[nt] + sn*32);
      bf16x8 af[2];
      #pragma unroll
      for (int mt = 0; mt < 2; mt++)
        af[mt] = *(const bf16x8*)(xcur + (mt*16 + col)*72 + kc*32 + quad*8);
      #pragma unroll
      for (int nt = 0; nt < 3; nt++)
        #pragma unroll
        for (int mt = 0; mt < 2; mt++)
          acc[mt][nt] = __builtin_amdgcn_mfma_f32_16x16x32_bf16(af[mt], bcur[nt], acc[mt][nt], 0, 0, 0);
      #pragma unroll
      for (int nt = 0; nt < 3; nt++) bcur[nt] = bnx[nt];
    }
    alignas(16) ushort us[8];
    us[0]=f2bf(g0.x); us[1]=f2bf(g0.y); us[2]=f2bf(g0.z); us[3]=f2bf(g0.w);
    us[4]=f2bf(g1.x); us[5]=f2bf(g1.y); us[6]=f2bf(g1.z); us[7]=f2bf(g1.w);
    *(uint4*)(&xa[(it + 1) & 1][sr*72+sc]) = *(uint4*)&us[0];
    __syncthreads();
  }

  #pragma unroll
  for (int nt = 0; nt < 3; nt++) {
    int n = nhalf + wave*48 + nt*16 + col;
    int mat = n >> 7, nw = n & 127;
    #pragma unroll
    for (int mt = 0; mt < 2; mt++) {
      int row0 = m0 + mt*16 + quad*4;
      #pragma unroll
      for (int r = 0; r < 4; r++) {
        int row = row0 + r;
        ushort val = f2bf(acc[mt][nt][r]);
        if (mat == 2) {
          int bb = row >> 12, s = row & 4095;
          vTo[((size_t)bb * H_ + nw) * S_ + s] = val;
        } else {
          ushort* dst = (mat == 0 ? qo : ko);
          dst[(size_t)row * H_ + nw] = val;
        }
      }
    }
  }
}

// ---------- kernel 3: causal flash, split-K, 4-wave WG, LDS-staged K ----------
// grid (c=8, y=64 tiles reversed, b=4); WG owns 64 q-rows x 512-key chunk.
// K double-buffered in LDS (XOR-swizzled 16B units); V^T direct per-wave.
#define CHUNK_ 512
__global__ __launch_bounds__(256, 3) void flash_kernel(const ushort* __restrict__ q,
    const ushort* __restrict__ k, const ushort* __restrict__ vT,
    float* __restrict__ Opart, float* __restrict__ ml) {
  const float SL2E = 0.08838834764831845f * 1.44269504088896340736f;
  int c = blockIdx.x;
  int tile = 63 - (int)blockIdx.y;            // heavy tiles first
  int b = blockIdx.z;
  if (tile < 8 * c) return;
  int a = tile >> 3, rr = tile & 7;
  int slot = b * 288 + (a + 1) * (4 * a + rr) + c;

  int wave = threadIdx.x >> 6, lane = threadIdx.x & 63;
  int col = lane & 15, quad = lane >> 4;
  int xa16 = ((lane ^ 16) << 2);
  int xa32 = ((lane ^ 32) << 2);
  int q0 = tile * 64 + wave * 16;
  const ushort* qb = q + (size_t)b * S_ * H_;
  const ushort* kbp = k + (size_t)b * S_ * H_;
  const ushort* vb = vT + (size_t)b * H_ * S_;

  __shared__ ushort kl[2][32 * 128];          // K block: [key][16B-unit ^ (key&15)]
  __shared__ ushort plds[4][16 * 40];
  ushort* pw = &plds[wave][0];

  bf16x8 qf[4];
  const ushort* qptr = qb + (size_t)(q0 + col) * H_ + quad * 8;
  #pragma unroll
  for (int kc = 0; kc < 4; kc++) qf[kc] = *(const bf16x8*)(qptr + kc * 32);

  f32x4 O[8];
  #pragma unroll
  for (int d = 0; d < 8; d++) O[d] = (f32x4){0.f,0.f,0.f,0.f};
  float m_i = -1e30f, l_i = 0.f;

  const int c0 = c * CHUNK_;
  const int kendWG = min(c0 + CHUNK_, tile * 64 + 64);  // wave-3 bound (WG-uniform)
  const int nblk = (kendWG - c0 + 31) >> 5;
  const int qlim = q0 + 15;                   // this wave's last valid key

  // staging lanes: this wave stages keys [wave*8, wave*8+8) of each block
  const int sk0 = wave * 8 + (lane >> 4);     // group-0 key (0..31 across waves)
  const int sd = lane & 15;                   // 16B unit
  // swizzled global unit offsets (in ushorts)
  const int gu0 = (sd ^ (sk0 & 15)) * 8;
  const int gu1 = (sd ^ ((sk0 + 4) & 15)) * 8;
  ushort* ld0 = &kl[0][(sk0)*128 + sd*8];
  ushort* ld1 = &kl[0][(sk0+4)*128 + sd*8];
  const size_t lbuf = 32 * 128;

  const ushort* vbase = vb + (size_t)col * S_ + c0 + quad * 8;

  // prologue: stage block 0 into kl[0]
  {
    const ushort* kp = kbp + (size_t)(c0 + sk0) * H_;
    uint4 a0 = *(const uint4*)(kp + gu0);
    uint4 a1 = *(const uint4*)(kp + 4 * H_ + gu1);
    *(uint4*)ld0 = a0;
    *(uint4*)ld1 = a1;
  }
  __syncthreads();

  for (int ib = 0; ib < nblk; ib++) {
    const int kb0 = c0 + ib * 32;
    // stage next block into the other buffer
    if (ib + 1 < nblk) {
      const ushort* kp = kbp + (size_t)(kb0 + 32 + sk0) * H_;
      uint4 a0 = *(const uint4*)(kp + gu0);
      uint4 a1 = *(const uint4*)(kp + 4 * H_ + gu1);
      size_t off = ((ib + 1) & 1) * lbuf;
      *(uint4*)(ld0 + off) = a0;
      *(uint4*)(ld1 + off) = a1;
    }
    if (kb0 <= qlim) {                        // wave-uniform: skip fully-masked blocks
      // V fragments (global, long latency — issue before softmax work)
      bf16x8 vf[8];
      #pragma unroll
      for (int d = 0; d < 8; d++)
        vf[d] = *(const bf16x8*)(vbase + ib * 32 + (size_t)(d * 16) * S_);

      // K fragments from LDS (swizzled)
      const ushort* kcur = &kl[ib & 1][0];
      bf16x8 kf0[4], kf1[4];
      #pragma unroll
      for (int kc = 0; kc < 4; kc++) {
        int u = quad + kc * 4;
        kf0[kc] = *(const bf16x8*)(kcur + col*128        + ((u ^ (col & 15)) * 8));
        kf1[kc] = *(const bf16x8*)(kcur + (16 + col)*128 + ((u ^ (col & 15)) * 8));
      }
      f32x4 st0 = (f32x4){0.f,0.f,0.f,0.f}, st1 = (f32x4){0.f,0.f,0.f,0.f};
      #pragma unroll
      for (int kc = 0; kc < 4; kc++) {
        st0 = __builtin_amdgcn_mfma_f32_16x16x32_bf16(kf0[kc], qf[kc], st0, 0, 0, 0);
        st1 = __builtin_amdgcn_mfma_f32_16x16x32_bf16(kf1[kc], qf[kc], st1, 0, 0, 0);
      }
      float s[8];
      #pragma unroll
      for (int r = 0; r < 4; r++) { s[r] = st0[r]; s[4+r] = st1[r]; }
      if (kb0 + 31 > q0) {
        #pragma unroll
        for (int r = 0; r < 4; r++) {
          if (kb0 + quad*4 + r      > q0 + col) s[r]   = -1e30f;
          if (kb0 + 16 + quad*4 + r > q0 + col) s[4+r] = -1e30f;
        }
      }
      float cm = s[0];
      #pragma unroll
      for (int j = 1; j < 8; j++) cm = fmaxf(cm, s[j]);
      cm = fmaxf(cm, bpermf(xa16, cm));
      cm = fmaxf(cm, bpermf(xa32, cm));
      float mn = fmaxf(m_i, cm);
      float alpha = exp2f((m_i - mn) * SL2E);
      m_i = mn;
      float p[8], rs = 0.f;
      #pragma unroll
      for (int j = 0; j < 8; j++) { p[j] = exp2f((s[j] - mn) * SL2E); rs += p[j]; }
      rs += bpermf(xa16, rs);
      rs += bpermf(xa32, rs);
      l_i = l_i * alpha + rs;
      #pragma unroll
      for (int d = 0; d < 8; d++) O[d] *= alpha;
      {
        unsigned* pq = (unsigned*)(pw + col * 40);
        unsigned w0 = (unsigned)f2bf(p[0]) | ((unsigned)f2bf(p[1]) << 16);
        unsigned w1 = (unsigned)f2bf(p[2]) | ((unsigned)f2bf(p[3]) << 16);
        unsigned w2 = (unsigned)f2bf(p[4]) | ((unsigned)f2bf(p[5]) << 16);
        unsigned w3 = (unsigned)f2bf(p[6]) | ((unsigned)f2bf(p[7]) << 16);
        pq[quad*2]       = w0;
        pq[quad*2 + 1]   = w1;
        pq[8 + quad*2]     = w2;
        pq[8 + quad*2 + 1] = w3;
      }
      bf16x8 pf = *(const bf16x8*)(pw + col * 40 + quad * 8);
      #pragma unroll
      for (int d = 0; d < 8; d++)
        O[d] = __builtin_amdgcn_mfma_f32_16x16x32_bf16(vf[d], pf, O[d], 0, 0, 0);
    }
    __syncthreads();
  }

  float* Op = Opart + (size_t)slot * (64 * 128) + (size_t)(wave*16 + col) * 128 + quad * 4;
  #pragma unroll
  for (int d = 0; d < 8; d++)
    *(f32x4*)(Op + d * 16) = O[d];
  if (quad == 0) {
    float2* mlp = (float2*)(ml + (size_t)slot * 128 + (size_t)(wave*16 + col) * 2);
    *mlp = make_float2(m_i, l_i);
  }
}

// ---------- kernel 4: combine split-K partials ----------
__global__ __launch_bounds__(256) void combine_kernel(const float* __restrict__ Opart,
    const float* __restrict__ ml, float* __restrict__ out) {
  const float SL2E = 0.08838834764831845f * 1.44269504088896340736f;
  int tile = blockIdx.x, b = blockIdx.y;
  int a = tile >> 3, rr = tile & 7;
  int nc = a + 1;
  int base = b * 288 + (a + 1) * (4 * a + rr);
  int tid = threadIdx.x;
  int row = tid >> 2;
  int cs = (tid & 3) * 4;
  float m_c[8], l_c[8];
  float mstar = -1e30f;
  for (int ci = 0; ci < nc; ci++) {
    m_c[ci] = ml[(size_t)(base + ci) * 128 + row * 2];
    l_c[ci] = ml[(size_t)(base + ci) * 128 + row * 2 + 1];
    mstar = fmaxf(mstar, m_c[ci]);
  }
  float denom = 0.f;
  float w_c[8];
  for (int ci = 0; ci < nc; ci++) {
    w_c[ci] = exp2f((m_c[ci] - mstar) * SL2E);
    denom += w_c[ci] * l_c[ci];
  }
  float inv = 1.f / denom;
  f32x4 acc[8];
  #pragma unroll
  for (int i = 0; i < 8; i++) acc[i] = (f32x4){0.f,0.f,0.f,0.f};
  for (int ci = 0; ci < nc; ci++) {
    const float* Op = Opart + (size_t)(base + ci) * (64 * 128) + row * 128;
    float w = w_c[ci];
    #pragma unroll
    for (int i = 0; i < 8; i++) {
      f32x4 v = *(const f32x4*)(Op + cs + i * 16);
      acc[i] += w * v;
    }
  }
  float* o = out + ((size_t)(b * S_) + tile * 64 + row) * H_;
  #pragma unroll
  for (int i = 0; i < 8; i++) {
    f32x4 v = acc[i] * inv;
    *(f32x4*)(o + cs + i * 16) = v;
  }
}

extern "C" void kernel_launch(void* const* d_in, const int* in_sizes, int n_in,
                              void* d_out, int out_size, void* d_ws, size_t ws_size,
                              hipStream_t stream) {
  (void)in_sizes; (void)n_in; (void)out_size; (void)ws_size;
  const float* x  = (const float*)d_in[0];
  const float* Wq = (const float*)d_in[1];
  const float* Wk = (const float*)d_in[2];
  const float* Wv = (const float*)d_in[3];
  float* out = (float*)d_out;
  char* ws = (char*)d_ws;
  ushort* Wt = (ushort*)ws;
  ushort* qb = (ushort*)(ws + 786432);
  ushort* kb = qb + (size_t)M_ * H_;
  ushort* vT = kb + (size_t)M_ * H_;
  float* Opart = (float*)(ws + 786432 + 3 * (size_t)M_ * H_ * 2);
  float* ml = Opart + (size_t)1152 * 64 * 128;

  hipLaunchKernelGGL(wt_kernel,   dim3(384), dim3(256), 0, stream, Wq, Wk, Wv, Wt);
  hipLaunchKernelGGL(qkv_gemm,    dim3(512, 2), dim3(256), 0, stream, x, Wt, qb, kb, vT);
  hipLaunchKernelGGL(flash_kernel,dim3(8, 64, 4), dim3(256), 0, stream, qb, kb, vT, Opart, ml);
  hipLaunchKernelGGL(combine_kernel, dim3(64, 4), dim3(256), 0, stream, Opart, ml, out);
}

// Round 6
// 224.362 us; speedup vs baseline: 1.9246x; 1.3655x over previous
//
#include <hip/hip_runtime.h>

#define B_ 4
#define S_ 4096
#define E_ 1024
#define H_ 128
#define M_ (B_*S_)   // 16384

typedef __attribute__((ext_vector_type(8))) short bf16x8;
typedef __attribute__((ext_vector_type(4))) float f32x4;

__device__ inline ushort f2bf(float f) {
  union { float f; unsigned u; } v; v.f = f;
  unsigned r = v.u + 0x7fffu + ((v.u >> 16) & 1u);   // RNE
  return (ushort)(r >> 16);
}

__device__ inline float bpermf(int addr, float x) {
  union { float f; int i; } v; v.f = x;
  v.i = __builtin_amdgcn_ds_bpermute(addr, v.i);
  return v.f;
}

#define GLLDS16(g, l) __builtin_amdgcn_global_load_lds( \
    (const __attribute__((address_space(1))) void*)(g), \
    (__attribute__((address_space(3))) void*)(l), 16, 0, 0)

// ---------- kernel 1: W [1024][128] f32 (x3) -> Wt [3][128][1024] bf16 ----------
__global__ __launch_bounds__(256) void wt_kernel(const float* __restrict__ Wq,
    const float* __restrict__ Wk, const float* __restrict__ Wv,
    ushort* __restrict__ Wt) {
  int bid = blockIdx.x;               // 384 = 3 mats * 4 h-tiles * 32 e-tiles
  int mat = bid >> 7;
  int rem = bid & 127;
  int ht = rem >> 5, et = rem & 31;
  const float* W = mat == 0 ? Wq : (mat == 1 ? Wk : Wv);
  int e0 = et * 32, h0 = ht * 32;
  __shared__ float tl[32][33];
  int t = threadIdx.x;
  int r = t >> 3, c = (t & 7) << 2;
  const float4 f = *(const float4*)(W + (size_t)(e0 + r) * H_ + h0 + c);
  tl[r][c] = f.x; tl[r][c+1] = f.y; tl[r][c+2] = f.z; tl[r][c+3] = f.w;
  __syncthreads();
  ushort4 o;
  o.x = f2bf(tl[c+0][r]); o.y = f2bf(tl[c+1][r]);
  o.z = f2bf(tl[c+2][r]); o.w = f2bf(tl[c+3][r]);
  *(ushort4*)(Wt + ((size_t)mat*H_ + h0 + r) * E_ + e0 + c) = o;
}

// ---------- kernel 2: x f32 -> bf16 (memory-bound) ----------
__global__ __launch_bounds__(256) void xb_kernel(const float* __restrict__ x,
                                                 ushort* __restrict__ xb) {
  size_t i = ((size_t)blockIdx.x * 256 + threadIdx.x) * 8;
  float4 f0 = *(const float4*)(x + i);
  float4 f1 = *(const float4*)(x + i + 4);
  alignas(16) ushort us[8];
  us[0]=f2bf(f0.x); us[1]=f2bf(f0.y); us[2]=f2bf(f0.z); us[3]=f2bf(f0.w);
  us[4]=f2bf(f1.x); us[5]=f2bf(f1.y); us[6]=f2bf(f1.z); us[7]=f2bf(f1.w);
  *(uint4*)(xb + i) = *(uint4*)&us[0];
}

// ---------- kernel 3: QKV GEMM, m97-style: 128x128 tile, BK=64, global_load_lds ----------
// xb [16384][1024] bf16 @ Wt[mat] [128][1024] bf16 -> q/k rows, vT transposed
__global__ __launch_bounds__(256, 2) void qkv_gemm(const ushort* __restrict__ xb,
    const ushort* __restrict__ Wt, ushort* __restrict__ qo,
    ushort* __restrict__ ko, ushort* __restrict__ vTo) {
  const int m0 = blockIdx.x * 128;
  const int mat = blockIdx.y;
  const ushort* Bsrc = Wt + (size_t)mat * H_ * E_;
  __shared__ ushort As[2][128 * 64];
  __shared__ ushort Bs[2][128 * 64];
  const int tid = threadIdx.x;
  const int wave = tid >> 6, lane = tid & 63;
  const int col = lane & 15, quad = lane >> 4;
  const int wr = wave >> 1, wc = wave & 1;

  f32x4 acc[4][4];
  #pragma unroll
  for (int i = 0; i < 4; i++)
    #pragma unroll
    for (int j = 0; j < 4; j++) acc[i][j] = (f32x4){0.f,0.f,0.f,0.f};

  const int srow = lane >> 3;               // 0..7
  const int sunit = (lane & 7) ^ srow;      // XOR-swizzled 16B unit (stored at lane&7)
  const int gcol = sunit * 8;               // global ushort offset of the unit

  // stage A+B k-block `it` into buffer bufi
  #define STAGE_QKV(it, bufi) do { \
    _Pragma("unroll") \
    for (int j = 0; j < 4; j++) { \
      int rbase = wave*8 + j*32; \
      GLLDS16(xb + (size_t)(m0 + rbase + srow) * E_ + (it)*64 + gcol, \
              &As[bufi][rbase * 64]); \
      GLLDS16(Bsrc + (size_t)(rbase + srow) * E_ + (it)*64 + gcol, \
              &Bs[bufi][rbase * 64]); \
    } \
  } while (0)

  STAGE_QKV(0, 0);
  __syncthreads();

  for (int it = 0; it < 16; it++) {
    if (it < 15) STAGE_QKV(it + 1, (it + 1) & 1);
    const ushort* a = &As[it & 1][0];
    const ushort* bb = &Bs[it & 1][0];
    #pragma unroll
    for (int kc = 0; kc < 2; kc++) {
      bf16x8 af[4], bf[4];
      #pragma unroll
      for (int mi = 0; mi < 4; mi++) {
        int rr = wr*64 + mi*16 + col;
        af[mi] = *(const bf16x8*)(a + rr*64 + (((kc*4 + quad) ^ (col & 7)) * 8));
      }
      #pragma unroll
      for (int ni = 0; ni < 4; ni++) {
        int rr = wc*64 + ni*16 + col;
        bf[ni] = *(const bf16x8*)(bb + rr*64 + (((kc*4 + quad) ^ (col & 7)) * 8));
      }
      #pragma unroll
      for (int mi = 0; mi < 4; mi++)
        #pragma unroll
        for (int ni = 0; ni < 4; ni++)
          acc[mi][ni] = __builtin_amdgcn_mfma_f32_16x16x32_bf16(af[mi], bf[ni], acc[mi][ni], 0, 0, 0);
    }
    __syncthreads();
  }

  // epilogue
  if (mat == 2) {
    int bb = m0 >> 12;
    int sbase = (m0 & 4095) + wr * 64;
    #pragma unroll
    for (int ni = 0; ni < 4; ni++) {
      int n = wc*64 + ni*16 + col;
      #pragma unroll
      for (int mi = 0; mi < 4; mi++) {
        int s = sbase + mi*16 + quad*4;
        ushort4 o;
        o.x = f2bf(acc[mi][ni][0]); o.y = f2bf(acc[mi][ni][1]);
        o.z = f2bf(acc[mi][ni][2]); o.w = f2bf(acc[mi][ni][3]);
        *(ushort4*)(vTo + ((size_t)(bb * H_ + n)) * S_ + s) = o;
      }
    }
  } else {
    ushort* dst = (mat == 0 ? qo : ko);
    #pragma unroll
    for (int ni = 0; ni < 4; ni++) {
      int n = wc*64 + ni*16 + col;
      #pragma unroll
      for (int mi = 0; mi < 4; mi++) {
        int row = m0 + wr*64 + mi*16 + quad*4;
        #pragma unroll
        for (int r = 0; r < 4; r++)
          dst[(size_t)(row + r) * H_ + n] = f2bf(acc[mi][ni][r]);
      }
    }
  }
}

// ---------- kernel 4: causal flash, split-K, tile-PAIR per WG (2 chains/wave) ----------
// grid (c=8, tp=32 reversed, b=4); WG owns q-tiles {2tp, 2tp+1} x 512-key chunk.
#define CHUNK_ 512
__global__ __launch_bounds__(256, 2) void flash_kernel(const ushort* __restrict__ q,
    const ushort* __restrict__ k, const ushort* __restrict__ vT,
    float* __restrict__ Opart, float* __restrict__ ml) {
  const float SL2E = 0.08838834764831845f * 1.44269504088896340736f;
  int c = blockIdx.x;
  int tp = 31 - (int)blockIdx.y;              // heavy pairs first
  int b = blockIdx.z;
  if (tp < 4 * c) return;
  int tA = tp * 2, tB = tA + 1;
  int aA = tA >> 3, rA = tA & 7;
  int aB = tB >> 3, rB = tB & 7;
  int slotA = b * 288 + (aA + 1) * (4 * aA + rA) + c;
  int slotB = b * 288 + (aB + 1) * (4 * aB + rB) + c;

  int wave = threadIdx.x >> 6, lane = threadIdx.x & 63;
  int col = lane & 15, quad = lane >> 4;
  int xa16 = ((lane ^ 16) << 2);
  int xa32 = ((lane ^ 32) << 2);
  int q0A = tA * 64 + wave * 16;
  int q0B = q0A + 64;
  const ushort* qb = q + (size_t)b * S_ * H_;
  const ushort* kbp = k + (size_t)b * S_ * H_;
  const ushort* vb = vT + (size_t)b * H_ * S_;

  __shared__ ushort kl[2][32 * 128];          // K block, XOR-swizzled 16B units
  __shared__ ushort plds[4][2][16 * 40];      // P per (wave, tile)
  ushort* pwA = &plds[wave][0][0];
  ushort* pwB = &plds[wave][1][0];

  bf16x8 qfA[4], qfB[4];
  {
    const ushort* qpA = qb + (size_t)(q0A + col) * H_ + quad * 8;
    const ushort* qpB = qb + (size_t)(q0B + col) * H_ + quad * 8;
    #pragma unroll
    for (int kc = 0; kc < 4; kc++) {
      qfA[kc] = *(const bf16x8*)(qpA + kc * 32);
      qfB[kc] = *(const bf16x8*)(qpB + kc * 32);
    }
  }

  f32x4 OA[8], OB[8];
  #pragma unroll
  for (int d = 0; d < 8; d++) { OA[d] = (f32x4){0.f,0.f,0.f,0.f}; OB[d] = (f32x4){0.f,0.f,0.f,0.f}; }
  float mA = -1e30f, lA = 0.f, mB = -1e30f, lB = 0.f;

  const int c0 = c * CHUNK_;
  const int kendWG = min(c0 + CHUNK_, tB * 64 + 64);
  const int nblk = (kendWG - c0 + 31) >> 5;
  const int qlimA = q0A + 15, qlimB = q0B + 15;

  const int sk0 = wave * 8 + (lane >> 4);
  const int sd = lane & 15;
  const int gu0 = (sd ^ (sk0 & 15)) * 8;
  const int gu1 = (sd ^ ((sk0 + 4) & 15)) * 8;
  ushort* ld0 = &kl[0][(sk0) * 128 + sd * 8];
  ushort* ld1 = &kl[0][(sk0 + 4) * 128 + sd * 8];
  const size_t lbuf = 32 * 128;

  const ushort* vbase = vb + (size_t)col * S_ + c0 + quad * 8;

  {
    const ushort* kp = kbp + (size_t)(c0 + sk0) * H_;
    uint4 a0 = *(const uint4*)(kp + gu0);
    uint4 a1 = *(const uint4*)(kp + 4 * H_ + gu1);
    *(uint4*)ld0 = a0;
    *(uint4*)ld1 = a1;
  }
  __syncthreads();

  for (int ib = 0; ib < nblk; ib++) {
    const int kb0 = c0 + ib * 32;
    if (ib + 1 < nblk) {
      const ushort* kp = kbp + (size_t)(kb0 + 32 + sk0) * H_;
      uint4 a0 = *(const uint4*)(kp + gu0);
      uint4 a1 = *(const uint4*)(kp + 4 * H_ + gu1);
      size_t off = ((ib + 1) & 1) * lbuf;
      *(uint4*)(ld0 + off) = a0;
      *(uint4*)(ld1 + off) = a1;
    }
    if (kb0 <= qlimB) {                       // wave-uniform
      const bool doA = (kb0 <= qlimA);
      // shared V fragments (issue early)
      bf16x8 vf[8];
      #pragma unroll
      for (int d = 0; d < 8; d++)
        vf[d] = *(const bf16x8*)(vbase + ib * 32 + (size_t)(d * 16) * S_);
      // shared K fragments from LDS
      const ushort* kcur = &kl[ib & 1][0];
      bf16x8 kf0[4], kf1[4];
      #pragma unroll
      for (int kc = 0; kc < 4; kc++) {
        int u = quad + kc * 4;
        kf0[kc] = *(const bf16x8*)(kcur + col*128        + ((u ^ (col & 15)) * 8));
        kf1[kc] = *(const bf16x8*)(kcur + (16 + col)*128 + ((u ^ (col & 15)) * 8));
      }
      // scores for both tiles (independent chains)
      f32x4 sB0 = (f32x4){0.f,0.f,0.f,0.f}, sB1 = (f32x4){0.f,0.f,0.f,0.f};
      f32x4 sA0 = (f32x4){0.f,0.f,0.f,0.f}, sA1 = (f32x4){0.f,0.f,0.f,0.f};
      #pragma unroll
      for (int kc = 0; kc < 4; kc++) {
        sB0 = __builtin_amdgcn_mfma_f32_16x16x32_bf16(kf0[kc], qfB[kc], sB0, 0, 0, 0);
        sB1 = __builtin_amdgcn_mfma_f32_16x16x32_bf16(kf1[kc], qfB[kc], sB1, 0, 0, 0);
      }
      if (doA) {
        #pragma unroll
        for (int kc = 0; kc < 4; kc++) {
          sA0 = __builtin_amdgcn_mfma_f32_16x16x32_bf16(kf0[kc], qfA[kc], sA0, 0, 0, 0);
          sA1 = __builtin_amdgcn_mfma_f32_16x16x32_bf16(kf1[kc], qfA[kc], sA1, 0, 0, 0);
        }
      }
      // ---- tile B softmax ----
      {
        float s[8];
        #pragma unroll
        for (int r = 0; r < 4; r++) { s[r] = sB0[r]; s[4+r] = sB1[r]; }
        if (kb0 + 31 > q0B) {
          #pragma unroll
          for (int r = 0; r < 4; r++) {
            if (kb0 + quad*4 + r      > q0B + col) s[r]   = -1e30f;
            if (kb0 + 16 + quad*4 + r > q0B + col) s[4+r] = -1e30f;
          }
        }
        float cm = s[0];
        #pragma unroll
        for (int j = 1; j < 8; j++) cm = fmaxf(cm, s[j]);
        cm = fmaxf(cm, bpermf(xa16, cm));
        cm = fmaxf(cm, bpermf(xa32, cm));
        float mn = fmaxf(mB, cm);
        float alpha = exp2f((mB - mn) * SL2E);
        mB = mn;
        float p[8], rs = 0.f;
        #pragma unroll
        for (int j = 0; j < 8; j++) { p[j] = exp2f((s[j] - mn) * SL2E); rs += p[j]; }
        rs += bpermf(xa16, rs);
        rs += bpermf(xa32, rs);
        lB = lB * alpha + rs;
        #pragma unroll
        for (int d = 0; d < 8; d++) OB[d] *= alpha;
        unsigned* pq = (unsigned*)(pwB + col * 40);
        pq[quad*2]     = (unsigned)f2bf(p[0]) | ((unsigned)f2bf(p[1]) << 16);
        pq[quad*2+1]   = (unsigned)f2bf(p[2]) | ((unsigned)f2bf(p[3]) << 16);
        pq[8+quad*2]   = (unsigned)f2bf(p[4]) | ((unsigned)f2bf(p[5]) << 16);
        pq[8+quad*2+1] = (unsigned)f2bf(p[6]) | ((unsigned)f2bf(p[7]) << 16);
      }
      // ---- tile A softmax ----
      if (doA) {
        float s[8];
        #pragma unroll
        for (int r = 0; r < 4; r++) { s[r] = sA0[r]; s[4+r] = sA1[r]; }
        if (kb0 + 31 > q0A) {
          #pragma unroll
          for (int r = 0; r < 4; r++) {
            if (kb0 + quad*4 + r      > q0A + col) s[r]   = -1e30f;
            if (kb0 + 16 + quad*4 + r > q0A + col) s[4+r] = -1e30f;
          }
        }
        float cm = s[0];
        #pragma unroll
        for (int j = 1; j < 8; j++) cm = fmaxf(cm, s[j]);
        cm = fmaxf(cm, bpermf(xa16, cm));
        cm = fmaxf(cm, bpermf(xa32, cm));
        float mn = fmaxf(mA, cm);
        float alpha = exp2f((mA - mn) * SL2E);
        mA = mn;
        float p[8], rs = 0.f;
        #pragma unroll
        for (int j = 0; j < 8; j++) { p[j] = exp2f((s[j] - mn) * SL2E); rs += p[j]; }
        rs += bpermf(xa16, rs);
        rs += bpermf(xa32, rs);
        lA = lA * alpha + rs;
        #pragma unroll
        for (int d = 0; d < 8; d++) OA[d] *= alpha;
        unsigned* pq = (unsigned*)(pwA + col * 40);
        pq[quad*2]     = (unsigned)f2bf(p[0]) | ((unsigned)f2bf(p[1]) << 16);
        pq[quad*2+1]   = (unsigned)f2bf(p[2]) | ((unsigned)f2bf(p[3]) << 16);
        pq[8+quad*2]   = (unsigned)f2bf(p[4]) | ((unsigned)f2bf(p[5]) << 16);
        pq[8+quad*2+1] = (unsigned)f2bf(p[6]) | ((unsigned)f2bf(p[7]) << 16);
      }
      // ---- PV for both ----
      {
        bf16x8 pfB = *(const bf16x8*)(pwB + col * 40 + quad * 8);
        #pragma unroll
        for (int d = 0; d < 8; d++)
          OB[d] = __builtin_amdgcn_mfma_f32_16x16x32_bf16(vf[d], pfB, OB[d], 0, 0, 0);
        if (doA) {
          bf16x8 pfA = *(const bf16x8*)(pwA + col * 40 + quad * 8);
          #pragma unroll
          for (int d = 0; d < 8; d++)
            OA[d] = __builtin_amdgcn_mfma_f32_16x16x32_bf16(vf[d], pfA, OA[d], 0, 0, 0);
        }
      }
    }
    __syncthreads();
  }

  float* OpA = Opart + (size_t)slotA * (64 * 128) + (size_t)(wave*16 + col) * 128 + quad * 4;
  float* OpB = Opart + (size_t)slotB * (64 * 128) + (size_t)(wave*16 + col) * 128 + quad * 4;
  #pragma unroll
  for (int d = 0; d < 8; d++) {
    *(f32x4*)(OpA + d * 16) = OA[d];
    *(f32x4*)(OpB + d * 16) = OB[d];
  }
  if (quad == 0) {
    *(float2*)(ml + (size_t)slotA * 128 + (size_t)(wave*16 + col) * 2) = make_float2(mA, lA);
    *(float2*)(ml + (size_t)slotB * 128 + (size_t)(wave*16 + col) * 2) = make_float2(mB, lB);
  }
}

// ---------- kernel 5: combine split-K partials ----------
__global__ __launch_bounds__(256) void combine_kernel(const float* __restrict__ Opart,
    const float* __restrict__ ml, float* __restrict__ out) {
  const float SL2E = 0.08838834764831845f * 1.44269504088896340736f;
  int tile = blockIdx.x, b = blockIdx.y;
  int a = tile >> 3, rr = tile & 7;
  int nc = a + 1;
  int base = b * 288 + (a + 1) * (4 * a + rr);
  int tid = threadIdx.x;
  int row = tid >> 2;
  int cs = (tid & 3) * 4;
  float m_c[8], l_c[8];
  float mstar = -1e30f;
  for (int ci = 0; ci < nc; ci++) {
    m_c[ci] = ml[(size_t)(base + ci) * 128 + row * 2];
    l_c[ci] = ml[(size_t)(base + ci) * 128 + row * 2 + 1];
    mstar = fmaxf(mstar, m_c[ci]);
  }
  float denom = 0.f;
  float w_c[8];
  for (int ci = 0; ci < nc; ci++) {
    w_c[ci] = exp2f((m_c[ci] - mstar) * SL2E);
    denom += w_c[ci] * l_c[ci];
  }
  float inv = 1.f / denom;
  f32x4 acc[8];
  #pragma unroll
  for (int i = 0; i < 8; i++) acc[i] = (f32x4){0.f,0.f,0.f,0.f};
  for (int ci = 0; ci < nc; ci++) {
    const float* Op = Opart + (size_t)(base + ci) * (64 * 128) + row * 128;
    float w = w_c[ci];
    #pragma unroll
    for (int i = 0; i < 8; i++) {
      f32x4 v = *(const f32x4*)(Op + cs + i * 16);
      acc[i] += w * v;
    }
  }
  float* o = out + ((size_t)(b * S_) + tile * 64 + row) * H_;
  #pragma unroll
  for (int i = 0; i < 8; i++) {
    f32x4 v = acc[i] * inv;
    *(f32x4*)(o + cs + i * 16) = v;
  }
}

extern "C" void kernel_launch(void* const* d_in, const int* in_sizes, int n_in,
                              void* d_out, int out_size, void* d_ws, size_t ws_size,
                              hipStream_t stream) {
  (void)in_sizes; (void)n_in; (void)out_size; (void)ws_size;
  const float* x  = (const float*)d_in[0];
  const float* Wq = (const float*)d_in[1];
  const float* Wk = (const float*)d_in[2];
  const float* Wv = (const float*)d_in[3];
  float* out = (float*)d_out;
  char* ws = (char*)d_ws;
  ushort* Wt = (ushort*)ws;                                        // 768 KB
  ushort* qb = (ushort*)(ws + 786432);                             // 4 MB each
  ushort* kb = qb + (size_t)M_ * H_;
  ushort* vT = kb + (size_t)M_ * H_;
  float* Opart = (float*)(ws + 786432 + 3 * (size_t)M_ * H_ * 2);  // 36 MB
  float* ml = Opart + (size_t)1152 * 64 * 128;                     // 0.6 MB
  ushort* xbuf = (ushort*)Opart;   // alias: xb dead before flash writes Opart

  hipLaunchKernelGGL(wt_kernel,   dim3(384), dim3(256), 0, stream, Wq, Wk, Wv, Wt);
  hipLaunchKernelGGL(xb_kernel,   dim3(8192), dim3(256), 0, stream, x, xbuf);
  hipLaunchKernelGGL(qkv_gemm,    dim3(128, 3), dim3(256), 0, stream, xbuf, Wt, qb, kb, vT);
  hipLaunchKernelGGL(flash_kernel,dim3(8, 32, 4), dim3(256), 0, stream, qb, kb, vT, Opart, ml);
  hipLaunchKernelGGL(combine_kernel, dim3(64, 4), dim3(256), 0, stream, Opart, ml, out);
}